// Round 1
// baseline (591.819 us; speedup 1.0000x reference)
//
#include <hip/hip_runtime.h>

typedef __attribute__((ext_vector_type(8))) short bf16x8;
typedef __attribute__((ext_vector_type(4))) float f32x4;
typedef unsigned short u16;

__device__ __forceinline__ u16 f2b(float f) {
  union { float f; unsigned u; } v; v.f = f;
  return (u16)((v.u + 0x7FFFu + ((v.u >> 16) & 1u)) >> 16);
}

__device__ __forceinline__ void gload16(const void* g, void* l) {
  __builtin_amdgcn_global_load_lds((__attribute__((address_space(1))) void*)(g),
                                   (__attribute__((address_space(3))) void*)(l),
                                   16, 0, 0);
}

// ---------------- fp32 -> bf16 ----------------
__global__ __launch_bounds__(256) void f2b_kernel(const float4* __restrict__ in,
                                                  u16* __restrict__ out, int n4) {
  int i = blockIdx.x * 256 + threadIdx.x;
  const int stride = gridDim.x * 256;
  for (; i < n4; i += stride) {
    float4 v = in[i];
    unsigned long long pk = (unsigned long long)f2b(v.x) |
                            ((unsigned long long)f2b(v.y) << 16) |
                            ((unsigned long long)f2b(v.z) << 32) |
                            ((unsigned long long)f2b(v.w) << 48);
    *(unsigned long long*)(out + (size_t)i * 4) = pk;
  }
}

// ---------------- embedding * sqrt(D) + sinusoidal PE ----------------
__global__ __launch_bounds__(256) void embed_pe(const int* __restrict__ tok,
    const float* __restrict__ emb, float* __restrict__ xf, u16* __restrict__ xb) {
  const int s = blockIdx.x;
  const int i = threadIdx.x;                       // frequency index 0..255
  const int t = tok[s];
  const float div = __expf((float)(2 * i) * -0.017988946039015984f); // -ln(1e4)/512
  const float ang = (float)s * div;
  const float sv = sinf(ang), cv = cosf(ang);
  const float* e = emb + (size_t)t * 512 + 2 * i;
  const float x0 = e[0] * 22.627416997969522f + sv;   // sqrt(512)
  const float x1 = e[1] * 22.627416997969522f + cv;
  const size_t o = (size_t)s * 512 + 2 * i;
  xf[o] = x0; xf[o + 1] = x1;
  xb[o] = f2b(x0); xb[o + 1] = f2b(x1);
}

// ---------------- GEMM: C = A(MxK,bf16) . B(NxK,bf16)^T + bias ----------------
// m97 structure: 128x128 tile, BK=32, 4 waves (2x2, 64x64 each), global_load_lds w=16.
template<int RELU, int WF32, int WB16>
__global__ __launch_bounds__(256)
void gemm_bt(const u16* __restrict__ A, const u16* __restrict__ B,
             const float* __restrict__ bias, float* __restrict__ Cf,
             u16* __restrict__ Cb, int M, int N, int K)
{
  __shared__ __align__(16) u16 As[128 * 32];
  __shared__ __align__(16) u16 Bs[128 * 32];
  const int tid = threadIdx.x;
  const int wid = tid >> 6, lane = tid & 63;
  const int lo = lane & 15, hi = lane >> 4;
  const int nbn = N >> 7;
  // XCD-aware bijective swizzle (all grids are multiples of 8)
  const int cpx = (int)gridDim.x >> 3;
  const int bid = blockIdx.x;
  const int swz = (bid & 7) * cpx + (bid >> 3);
  const int bi = swz / nbn, bj = swz - bi * nbn;
  const size_t row0 = (size_t)bi << 7, col0 = (size_t)bj << 7;
  const int wr = (wid >> 1) << 6, wc = (wid & 1) << 6;
  const int r0 = (wid << 5) + (lane >> 2);      // staging row within tile
  const int c0 = (lane & 3) << 3;               // staging col (elements)

  f32x4 acc[4][4] = {};

  for (int k0 = 0; k0 < K; k0 += 32) {
    __syncthreads();  // previous iter's LDS reads done
    gload16(A + (row0 + r0) * (size_t)K + k0 + c0,        &As[wid * 1024]);
    gload16(A + (row0 + r0 + 16) * (size_t)K + k0 + c0,   &As[wid * 1024 + 512]);
    gload16(B + (col0 + r0) * (size_t)K + k0 + c0,        &Bs[wid * 1024]);
    gload16(B + (col0 + r0 + 16) * (size_t)K + k0 + c0,   &Bs[wid * 1024 + 512]);
    __syncthreads();  // compiler drains vmcnt before barrier
    bf16x8 af[4], bfr[4];
#pragma unroll
    for (int m = 0; m < 4; ++m)
      af[m] = *(const bf16x8*)&As[(wr + m * 16 + lo) * 32 + hi * 8];
#pragma unroll
    for (int n = 0; n < 4; ++n)
      bfr[n] = *(const bf16x8*)&Bs[(wc + n * 16 + lo) * 32 + hi * 8];
#pragma unroll
    for (int m = 0; m < 4; ++m)
#pragma unroll
      for (int n = 0; n < 4; ++n)
        acc[m][n] = __builtin_amdgcn_mfma_f32_16x16x32_bf16(af[m], bfr[n], acc[m][n], 0, 0, 0);
  }

#pragma unroll
  for (int m = 0; m < 4; ++m)
#pragma unroll
    for (int n = 0; n < 4; ++n) {
      const size_t c = col0 + wc + n * 16 + lo;
      const float bv = bias[c];
#pragma unroll
      for (int i = 0; i < 4; ++i) {
        const size_t r = row0 + wr + m * 16 + hi * 4 + i;  // C row=(lane>>4)*4+reg
        float v = acc[m][n][i] + bv;
        if (RELU) v = fmaxf(v, 0.0f);
        if (WF32) Cf[r * (size_t)N + c] = v;
        if (WB16) Cb[r * (size_t)N + c] = f2b(v);
      }
    }
}

// ---------------- chunk attention: attend over nc=4 chunks ----------------
// one wave per (intra-chunk position p, head h); lane = head-dim d
__global__ __launch_bounds__(64)
void chunk_attn(const float* __restrict__ qkv, u16* __restrict__ out) {
  const int p = blockIdx.x, h = blockIdx.y, d = threadIdx.x;
  float q[4], k[4], v[4];
#pragma unroll
  for (int c = 0; c < 4; ++c) {
    const float* b = qkv + (size_t)((c << 10) + p) * 1536 + (h << 6) + d;
    q[c] = b[0]; k[c] = b[512]; v[c] = b[1024];
  }
  float sc[4][4];
#pragma unroll
  for (int i = 0; i < 4; ++i)
#pragma unroll
    for (int j = 0; j < 4; ++j) sc[i][j] = q[i] * k[j];
#pragma unroll
  for (int mask = 1; mask < 64; mask <<= 1)
#pragma unroll
    for (int i = 0; i < 4; ++i)
#pragma unroll
      for (int j = 0; j < 4; ++j) sc[i][j] += __shfl_xor(sc[i][j], mask);
#pragma unroll
  for (int i = 0; i < 4; ++i) {
    float s0 = sc[i][0] * 0.125f, s1 = sc[i][1] * 0.125f,
          s2 = sc[i][2] * 0.125f, s3 = sc[i][3] * 0.125f;
    const float mx = fmaxf(fmaxf(s0, s1), fmaxf(s2, s3));
    const float e0 = __expf(s0 - mx), e1 = __expf(s1 - mx),
                e2 = __expf(s2 - mx), e3 = __expf(s3 - mx);
    const float inv = 1.0f / (e0 + e1 + e2 + e3);
    const float o = (e0 * v[0] + e1 * v[1] + e2 * v[2] + e3 * v[3]) * inv;
    out[(size_t)((i << 10) + p) * 512 + (h << 6) + d] = f2b(o);
  }
}

// ---------------- global flash attention (L=4096, hd=64, 8 heads) ----------------
// block = 4 waves, 64 q-rows (16/wave); KV tiles of 64; XOR-swizzled LDS (T2)
__global__ __launch_bounds__(256)
void flash_attn(const u16* __restrict__ qkv, u16* __restrict__ out) {
  __shared__ __align__(16) u16 Ks[64 * 64];
  __shared__ __align__(16) u16 Vt[64 * 64];   // transposed: [d][j]
  __shared__ __align__(16) u16 Pls[64 * 64];  // wave-private row blocks
  const int tid = threadIdx.x, wid = tid >> 6, lane = tid & 63;
  const int lo = lane & 15, hi = lane >> 4;
  const int q0 = blockIdx.x << 6, h = blockIdx.y;
  const int hoff = h << 6;
  char* KsB = (char*)Ks; char* VtB = (char*)Vt; char* PlB = (char*)Pls;

  // Q fragments hoisted to registers (rows wid*16+lo)
  bf16x8 qf[2];
#pragma unroll
  for (int kh = 0; kh < 2; ++kh)
    qf[kh] = *(const bf16x8*)(qkv + (size_t)(q0 + wid * 16 + lo) * 1536 + hoff + kh * 32 + hi * 8);

  f32x4 o[4] = {};
  float mr[4] = {-3e38f, -3e38f, -3e38f, -3e38f};
  float lr[4] = {0.f, 0.f, 0.f, 0.f};

  const int krow = tid >> 3, kchunk = tid & 7;   // K staging
  const int vj = tid >> 2, vq = tid & 3;         // V staging

  for (int kv0 = 0; kv0 < 4096; kv0 += 64) {
    // stage K (swizzled rows) -- 2 passes of 32 rows
#pragma unroll
    for (int p = 0; p < 2; ++p) {
      const int row = krow + p * 32;
      bf16x8 kv = *(const bf16x8*)(qkv + (size_t)(kv0 + row) * 1536 + 512 + hoff + kchunk * 8);
      *(bf16x8*)(KsB + ((row * 128 + kchunk * 16) ^ ((row & 7) << 4))) = kv;
    }
    // stage V transposed: Vt[d][j] = V[j][d]
    {
      const u16* vb = qkv + (size_t)(kv0 + vj) * 1536 + 1024 + hoff + vq * 16;
      bf16x8 a0 = *(const bf16x8*)(vb);
      bf16x8 a1 = *(const bf16x8*)(vb + 8);
#pragma unroll
      for (int dd = 0; dd < 8; ++dd) {
        const int d0 = vq * 16 + dd, d1 = d0 + 8;
        *(u16*)(VtB + ((d0 * 128 + 2 * vj) ^ ((d0 & 7) << 4))) = (u16)a0[dd];
        *(u16*)(VtB + ((d1 * 128 + 2 * vj) ^ ((d1 & 7) << 4))) = (u16)a1[dd];
      }
    }
    __syncthreads();

    // QK^T -> S (C layout: row=hi*4+i, col=n*16+lo), scaled by 1/8
    f32x4 s[4] = {};
#pragma unroll
    for (int n = 0; n < 4; ++n) {
      const int key = n * 16 + lo;
#pragma unroll
      for (int kh = 0; kh < 2; ++kh) {
        bf16x8 kf = *(const bf16x8*)(KsB + ((key * 128 + kh * 64 + hi * 16) ^ ((key & 7) << 4)));
        s[n] = __builtin_amdgcn_mfma_f32_16x16x32_bf16(qf[kh], kf, s[n], 0, 0, 0);
      }
      s[n] *= 0.125f;
    }

    // in-register online softmax (reduce over the 16 lo-lanes of each hi group)
    float tmax[4];
#pragma unroll
    for (int i = 0; i < 4; ++i) {
      float t = fmaxf(fmaxf(s[0][i], s[1][i]), fmaxf(s[2][i], s[3][i]));
#pragma unroll
      for (int mask = 1; mask < 16; mask <<= 1) t = fmaxf(t, __shfl_xor(t, mask));
      tmax[i] = t;
    }
    float sc[4], rs[4];
#pragma unroll
    for (int i = 0; i < 4; ++i) {
      const float mn = fmaxf(mr[i], tmax[i]);
      sc[i] = __expf(mr[i] - mn);
      mr[i] = mn;
      rs[i] = 0.f;
    }
    const int prow_base = wid * 16 + hi * 4;
#pragma unroll
    for (int n = 0; n < 4; ++n)
#pragma unroll
      for (int i = 0; i < 4; ++i) {
        const float pv = __expf(s[n][i] - mr[i]);
        rs[i] += pv;
        const int row = prow_base + i;
        *(u16*)(PlB + (((row * 64 + n * 16 + lo) * 2) ^ ((row & 7) << 4))) = f2b(pv);
      }
#pragma unroll
    for (int i = 0; i < 4; ++i) {
#pragma unroll
      for (int mask = 1; mask < 16; mask <<= 1) rs[i] += __shfl_xor(rs[i], mask);
      lr[i] = lr[i] * sc[i] + rs[i];
#pragma unroll
      for (int n = 0; n < 4; ++n) o[n][i] *= sc[i];
    }

    // PV: O += P . V  (P wave-private in LDS; Vt gives contiguous-k B frags)
#pragma unroll
    for (int kh = 0; kh < 2; ++kh) {
      const int prow = wid * 16 + lo;
      bf16x8 pa = *(const bf16x8*)(PlB + ((prow * 128 + kh * 64 + hi * 16) ^ ((lo & 7) << 4)));
#pragma unroll
      for (int n = 0; n < 4; ++n) {
        const int vd = n * 16 + lo;
        bf16x8 vf = *(const bf16x8*)(VtB + ((vd * 128 + kh * 64 + hi * 16) ^ ((vd & 7) << 4)));
        o[n] = __builtin_amdgcn_mfma_f32_16x16x32_bf16(pa, vf, o[n], 0, 0, 0);
      }
    }
    __syncthreads();  // before next tile overwrites Ks/Vt
  }

#pragma unroll
  for (int n = 0; n < 4; ++n)
#pragma unroll
    for (int i = 0; i < 4; ++i) {
      const int r = q0 + wid * 16 + hi * 4 + i;
      out[(size_t)r * 512 + hoff + n * 16 + lo] = f2b(o[n][i] / lr[i]);
    }
}

// ---------------- residual add + LayerNorm (writes f32 + bf16) ----------------
__global__ __launch_bounds__(256)
void add_ln(const float* __restrict__ a, const float* __restrict__ b,
            const float* __restrict__ g, const float* __restrict__ be,
            float* __restrict__ of, u16* __restrict__ ob) {
  const int wid = threadIdx.x >> 6, lane = threadIdx.x & 63;
  const int row = blockIdx.x * 4 + wid;
  const size_t base = (size_t)row * 512 + lane * 8;
  float4 a0 = *(const float4*)(a + base), a1 = *(const float4*)(a + base + 4);
  float4 b0 = *(const float4*)(b + base), b1 = *(const float4*)(b + base + 4);
  float x[8] = {a0.x + b0.x, a0.y + b0.y, a0.z + b0.z, a0.w + b0.w,
                a1.x + b1.x, a1.y + b1.y, a1.z + b1.z, a1.w + b1.w};
  float s = 0.f, sq = 0.f;
#pragma unroll
  for (int j = 0; j < 8; ++j) { s += x[j]; sq += x[j] * x[j]; }
#pragma unroll
  for (int mask = 1; mask < 64; mask <<= 1) {
    s += __shfl_xor(s, mask);
    sq += __shfl_xor(sq, mask);
  }
  const float mean = s * (1.0f / 512.0f);
  const float var = sq * (1.0f / 512.0f) - mean * mean;
  const float rstd = rsqrtf(var + 1e-5f);
  float4 g0 = *(const float4*)(g + lane * 8), g1 = *(const float4*)(g + lane * 8 + 4);
  float4 e0 = *(const float4*)(be + lane * 8), e1 = *(const float4*)(be + lane * 8 + 4);
  const float gg[8] = {g0.x, g0.y, g0.z, g0.w, g1.x, g1.y, g1.z, g1.w};
  const float bb[8] = {e0.x, e0.y, e0.z, e0.w, e1.x, e1.y, e1.z, e1.w};
#pragma unroll
  for (int j = 0; j < 8; ++j) {
    const float y = (x[j] - mean) * rstd * gg[j] + bb[j];
    of[base + j] = y;
    ob[base + j] = f2b(y);
  }
}

extern "C" void kernel_launch(void* const* d_in, const int* in_sizes, int n_in,
                              void* d_out, int out_size, void* d_ws, size_t ws_size,
                              hipStream_t stream) {
  (void)in_sizes; (void)n_in; (void)out_size; (void)ws_size;
  const int*   tokens = (const int*)d_in[0];
  const float* emb    = (const float*)d_in[1];
  const float* cwin   = (const float*)d_in[2];
  const float* cbin   = (const float*)d_in[3];
  const float* cwout  = (const float*)d_in[4];
  const float* cbout  = (const float*)d_in[5];
  const float* gwin   = (const float*)d_in[6];
  const float* gbin   = (const float*)d_in[7];
  const float* gwout  = (const float*)d_in[8];
  const float* gbout  = (const float*)d_in[9];
  const float* ln1g   = (const float*)d_in[10];
  const float* ln1b   = (const float*)d_in[11];
  const float* fw1    = (const float*)d_in[12];
  const float* fb1    = (const float*)d_in[13];
  const float* fw2    = (const float*)d_in[14];
  const float* fb2    = (const float*)d_in[15];
  const float* ln2g   = (const float*)d_in[16];
  const float* ln2b   = (const float*)d_in[17];
  const float* fcw    = (const float*)d_in[18];
  const float* fcb    = (const float*)d_in[19];
  float* out = (float*)d_out;

  char* ws = (char*)d_ws;
  size_t off = 0;
  auto alloc = [&](size_t bytes) -> void* {
    void* p = ws + off;
    off += (bytes + 255) & ~(size_t)255;
    return p;
  };
  u16*   xb   = (u16*)alloc((size_t)4096 * 512 * 2);
  float* xf   = (float*)alloc((size_t)4096 * 512 * 4);
  float* qkv1 = (float*)alloc((size_t)4096 * 1536 * 4);
  u16*   at1  = (u16*)alloc((size_t)4096 * 512 * 2);
  u16*   cab  = (u16*)alloc((size_t)4096 * 512 * 2);
  u16*   qkv2 = (u16*)alloc((size_t)4096 * 1536 * 2);
  u16*   at2  = (u16*)alloc((size_t)4096 * 512 * 2);
  float* gaf  = (float*)alloc((size_t)4096 * 512 * 4);
  float* x1f  = (float*)alloc((size_t)4096 * 512 * 4);
  u16*   x1b  = (u16*)alloc((size_t)4096 * 512 * 2);
  u16*   f1b  = (u16*)alloc((size_t)4096 * 2048 * 2);
  float* ff   = (float*)alloc((size_t)4096 * 512 * 4);
  float* x2f  = (float*)alloc((size_t)4096 * 512 * 4);
  u16*   x2b  = (u16*)alloc((size_t)4096 * 512 * 2);
  u16*   wcinb  = (u16*)alloc((size_t)1536 * 512 * 2);
  u16*   wcoutb = (u16*)alloc((size_t)512 * 512 * 2);
  u16*   wginb  = (u16*)alloc((size_t)1536 * 512 * 2);
  u16*   wgoutb = (u16*)alloc((size_t)512 * 512 * 2);
  u16*   wf1b   = (u16*)alloc((size_t)2048 * 512 * 2);
  u16*   wf2b   = (u16*)alloc((size_t)512 * 2048 * 2);
  u16*   wfcb   = (u16*)alloc((size_t)32000 * 512 * 2);

  // weight conversions
  f2b_kernel<<<512, 256, 0, stream>>>((const float4*)cwin,  wcinb,  1536 * 512 / 4);
  f2b_kernel<<<512, 256, 0, stream>>>((const float4*)cwout, wcoutb, 512 * 512 / 4);
  f2b_kernel<<<512, 256, 0, stream>>>((const float4*)gwin,  wginb,  1536 * 512 / 4);
  f2b_kernel<<<512, 256, 0, stream>>>((const float4*)gwout, wgoutb, 512 * 512 / 4);
  f2b_kernel<<<512, 256, 0, stream>>>((const float4*)fw1,   wf1b,   2048 * 512 / 4);
  f2b_kernel<<<512, 256, 0, stream>>>((const float4*)fw2,   wf2b,   512 * 2048 / 4);
  f2b_kernel<<<2048, 256, 0, stream>>>((const float4*)fcw,  wfcb,   32000 * 512 / 4);

  embed_pe<<<4096, 256, 0, stream>>>(tokens, emb, xf, xb);

  // chunk stage
  gemm_bt<0, 1, 0><<<384, 256, 0, stream>>>(xb, wcinb, cbin, qkv1, (u16*)nullptr, 4096, 1536, 512);
  chunk_attn<<<dim3(1024, 8), 64, 0, stream>>>(qkv1, at1);
  gemm_bt<0, 0, 1><<<128, 256, 0, stream>>>(at1, wcoutb, cbout, (float*)nullptr, cab, 4096, 512, 512);

  // global stage
  gemm_bt<0, 0, 1><<<384, 256, 0, stream>>>(cab, wginb, gbin, (float*)nullptr, qkv2, 4096, 1536, 512);
  flash_attn<<<dim3(64, 8), 256, 0, stream>>>(qkv2, at2);
  gemm_bt<0, 1, 0><<<128, 256, 0, stream>>>(at2, wgoutb, gbout, gaf, (u16*)nullptr, 4096, 512, 512);

  // post-norm encoder layer
  add_ln<<<1024, 256, 0, stream>>>(xf, gaf, ln1g, ln1b, x1f, x1b);
  gemm_bt<1, 0, 1><<<512, 256, 0, stream>>>(x1b, wf1b, fb1, (float*)nullptr, f1b, 4096, 2048, 512);
  gemm_bt<0, 1, 0><<<128, 256, 0, stream>>>(f1b, wf2b, fb2, ff, (u16*)nullptr, 4096, 512, 2048);
  add_ln<<<1024, 256, 0, stream>>>(x1f, ff, ln2g, ln2b, x2f, x2b);

  // vocab projection
  gemm_bt<0, 1, 0><<<8000, 256, 0, stream>>>(x2b, wfcb, fcb, out, (u16*)nullptr, 4096, 32000, 512);
}

// Round 2
// 546.599 us; speedup vs baseline: 1.0827x; 1.0827x over previous
//
#include <hip/hip_runtime.h>

typedef __attribute__((ext_vector_type(8))) short bf16x8;
typedef __attribute__((ext_vector_type(4))) float f32x4;
typedef unsigned short u16;

__device__ __forceinline__ u16 f2b(float f) {
  union { float f; unsigned u; } v; v.f = f;
  return (u16)((v.u + 0x7FFFu + ((v.u >> 16) & 1u)) >> 16);
}

__device__ __forceinline__ void gload16(const void* g, void* l) {
  __builtin_amdgcn_global_load_lds((__attribute__((address_space(1))) void*)(g),
                                   (__attribute__((address_space(3))) void*)(l),
                                   16, 0, 0);
}

// raw barrier with compiler memory fences (no vmcnt(0) drain, unlike __syncthreads)
__device__ __forceinline__ void mbar() {
  asm volatile("" ::: "memory");
  __builtin_amdgcn_s_barrier();
  asm volatile("" ::: "memory");
}

// ---------------- batched fp32 -> bf16 (all 7 weight tensors, one launch) ----------------
__device__ __forceinline__ void cv1(const float4* __restrict__ s, u16* __restrict__ d, int i) {
  float4 v = s[i];
  unsigned long long pk = (unsigned long long)f2b(v.x) |
                          ((unsigned long long)f2b(v.y) << 16) |
                          ((unsigned long long)f2b(v.z) << 32) |
                          ((unsigned long long)f2b(v.w) << 48);
  *(unsigned long long*)(d + (size_t)i * 4) = pk;
}

__global__ __launch_bounds__(256)
void f2b_multi(const float4* s0, u16* d0, const float4* s1, u16* d1,
               const float4* s2, u16* d2, const float4* s3, u16* d3,
               const float4* s4, u16* d4, const float4* s5, u16* d5,
               const float4* s6, u16* d6) {
  int i = blockIdx.x * 256 + threadIdx.x;
  const int stride = gridDim.x * 256;
  for (; i < 5144576; i += stride) {
    int j = i;
    if (j < 196608) { cv1(s0, d0, j); continue; }
    j -= 196608;
    if (j < 65536) { cv1(s1, d1, j); continue; }
    j -= 65536;
    if (j < 196608) { cv1(s2, d2, j); continue; }
    j -= 196608;
    if (j < 65536) { cv1(s3, d3, j); continue; }
    j -= 65536;
    if (j < 262144) { cv1(s4, d4, j); continue; }
    j -= 262144;
    if (j < 262144) { cv1(s5, d5, j); continue; }
    j -= 262144;
    cv1(s6, d6, j);
  }
}

// ---------------- embedding * sqrt(D) + sinusoidal PE ----------------
__global__ __launch_bounds__(256) void embed_pe(const int* __restrict__ tok,
    const float* __restrict__ emb, float* __restrict__ xf, u16* __restrict__ xb) {
  const int s = blockIdx.x;
  const int i = threadIdx.x;
  const int t = tok[s];
  const float div = __expf((float)(2 * i) * -0.017988946039015984f);
  const float ang = (float)s * div;
  const float sv = sinf(ang), cv = cosf(ang);
  const float* e = emb + (size_t)t * 512 + 2 * i;
  const float x0 = e[0] * 22.627416997969522f + sv;
  const float x1 = e[1] * 22.627416997969522f + cv;
  const size_t o = (size_t)s * 512 + 2 * i;
  xf[o] = x0; xf[o + 1] = x1;
  xb[o] = f2b(x0); xb[o + 1] = f2b(x1);
}

// ---------------- 128x128 m97-structure GEMM (small/medium gemms) ----------------
template<int RELU, int WF32, int WB16>
__global__ __launch_bounds__(256)
void gemm_bt(const u16* __restrict__ A, const u16* __restrict__ B,
             const float* __restrict__ bias, float* __restrict__ Cf,
             u16* __restrict__ Cb, int M, int N, int K)
{
  __shared__ __align__(16) u16 As[128 * 32];
  __shared__ __align__(16) u16 Bs[128 * 32];
  const int tid = threadIdx.x;
  const int wid = tid >> 6, lane = tid & 63;
  const int lo = lane & 15, hi = lane >> 4;
  const int nbn = N >> 7;
  const int cpx = (int)gridDim.x >> 3;
  const int bid = blockIdx.x;
  const int swz = (bid & 7) * cpx + (bid >> 3);
  const int bi = swz / nbn, bj = swz - bi * nbn;
  const size_t row0 = (size_t)bi << 7, col0 = (size_t)bj << 7;
  const int wr = (wid >> 1) << 6, wc = (wid & 1) << 6;
  const int r0 = (wid << 5) + (lane >> 2);
  const int c0 = (lane & 3) << 3;

  f32x4 acc[4][4] = {};

  for (int k0 = 0; k0 < K; k0 += 32) {
    __syncthreads();
    gload16(A + (row0 + r0) * (size_t)K + k0 + c0,      &As[wid * 1024]);
    gload16(A + (row0 + r0 + 16) * (size_t)K + k0 + c0, &As[wid * 1024 + 512]);
    gload16(B + (col0 + r0) * (size_t)K + k0 + c0,      &Bs[wid * 1024]);
    gload16(B + (col0 + r0 + 16) * (size_t)K + k0 + c0, &Bs[wid * 1024 + 512]);
    __syncthreads();
    bf16x8 af[4], bfr[4];
#pragma unroll
    for (int m = 0; m < 4; ++m)
      af[m] = *(const bf16x8*)&As[(wr + m * 16 + lo) * 32 + hi * 8];
#pragma unroll
    for (int n = 0; n < 4; ++n)
      bfr[n] = *(const bf16x8*)&Bs[(wc + n * 16 + lo) * 32 + hi * 8];
#pragma unroll
    for (int m = 0; m < 4; ++m)
#pragma unroll
      for (int n = 0; n < 4; ++n)
        acc[m][n] = __builtin_amdgcn_mfma_f32_16x16x32_bf16(af[m], bfr[n], acc[m][n], 0, 0, 0);
  }

#pragma unroll
  for (int m = 0; m < 4; ++m)
#pragma unroll
    for (int n = 0; n < 4; ++n) {
      const size_t c = col0 + wc + n * 16 + lo;
      const float bv = bias[c];
#pragma unroll
      for (int i = 0; i < 4; ++i) {
        const size_t r = row0 + wr + m * 16 + hi * 4 + i;
        float v = acc[m][n][i] + bv;
        if (RELU) v = fmaxf(v, 0.0f);
        if (WF32) Cf[r * (size_t)N + c] = v;
        if (WB16) Cb[r * (size_t)N + c] = f2b(v);
      }
    }
}

// ---------------- 256x256 8-phase GEMM (FC projection): counted vmcnt pipeline ----------------
template<int KC>
__global__ __launch_bounds__(512, 2)
void gemm256(const u16* __restrict__ A, const u16* __restrict__ B,
             const float* __restrict__ bias, float* __restrict__ C,
             int M, int N)
{
  constexpr int T = KC / 64;
  __shared__ __align__(16) u16 LA[2][256 * 64];
  __shared__ __align__(16) u16 LB[2][256 * 64];
  const int tid = threadIdx.x;
  const int wid = tid >> 6, lane = tid & 63;
  const int lo = lane & 15, hi = lane >> 4;
  const int nbn = N >> 8;
  const int cpx = (int)gridDim.x >> 3;
  const int bid = blockIdx.x;
  const int swz = (bid & 7) * cpx + (bid >> 3);
  const int bi = swz / nbn, bj = swz - bi * nbn;
  const size_t row0 = (size_t)bi << 8, col0 = (size_t)bj << 8;
  const int wrow = (wid >> 2) << 7;   // 0 / 128
  const int wcol = (wid & 3) << 6;    // 0..192

  // staging: per 8KB issue, wave wid covers rows wid*8..+8 of a 64-row chunk.
  // linear LDS dest; source col pre-swizzled: slice (l&7)^(l>>3)
  const int srow = (wid << 3) + (lane >> 3);
  const int scol = ((lane & 7) ^ (lane >> 3)) << 3;
  const u16* srcA = A + (row0 + srow) * (size_t)KC + scol;
  const u16* srcB = B + (col0 + srow) * (size_t)KC + scol;
  const int ldst = wid << 9;          // wid*8 rows * 64 el

  f32x4 acc[8][4] = {};

  auto stage = [&](int t, int b) {
    const size_t ko = (size_t)t * 64;
#pragma unroll
    for (int i = 0; i < 4; ++i)
      gload16(srcA + ko + (size_t)(i * 64) * KC, &LA[b][ldst + i * 4096]);
#pragma unroll
    for (int i = 0; i < 4; ++i)
      gload16(srcB + ko + (size_t)(i * 64) * KC, &LB[b][ldst + i * 4096]);
  };

  auto rd = [&](const u16* base, int row, int ks) -> bf16x8 {
    const int byte = row * 128 + ((((ks << 2) | hi) ^ (row & 7)) << 4);
    return *(const bf16x8*)((const char*)base + byte);
  };

  stage(0, 0);
  stage(1, 1);

  for (int t = 0; t < T; ++t) {
    const int b = t & 1;
    const u16* Ab = LA[b];
    const u16* Bb = LB[b];
    if (t + 1 < T) { asm volatile("s_waitcnt vmcnt(8)" ::: "memory"); }
    else           { asm volatile("s_waitcnt vmcnt(0)" ::: "memory"); }
    __builtin_amdgcn_sched_barrier(0);
    mbar();   // all waves' tile-t DMA landed

    bf16x8 afr[4], bfr[4];
#pragma unroll
    for (int ks = 0; ks < 2; ++ks) {
      // phase A: m 0..3, load B frags for this ks
#pragma unroll
      for (int m = 0; m < 4; ++m) afr[m] = rd(Ab, wrow + m * 16 + lo, ks);
#pragma unroll
      for (int n = 0; n < 4; ++n) bfr[n] = rd(Bb, wcol + n * 16 + lo, ks);
      mbar();
      asm volatile("s_waitcnt lgkmcnt(0)" ::: "memory");
      __builtin_amdgcn_sched_barrier(0);
      __builtin_amdgcn_s_setprio(1);
#pragma unroll
      for (int m = 0; m < 4; ++m)
#pragma unroll
        for (int n = 0; n < 4; ++n)
          acc[m][n] = __builtin_amdgcn_mfma_f32_16x16x32_bf16(afr[m], bfr[n], acc[m][n], 0, 0, 0);
      __builtin_amdgcn_s_setprio(0);
      mbar();
      // phase B: m 4..7 (reuse bfr)
#pragma unroll
      for (int m = 0; m < 4; ++m) afr[m] = rd(Ab, wrow + (4 + m) * 16 + lo, ks);
      mbar();
      asm volatile("s_waitcnt lgkmcnt(0)" ::: "memory");
      __builtin_amdgcn_sched_barrier(0);
      __builtin_amdgcn_s_setprio(1);
#pragma unroll
      for (int m = 0; m < 4; ++m)
#pragma unroll
        for (int n = 0; n < 4; ++n)
          acc[4 + m][n] = __builtin_amdgcn_mfma_f32_16x16x32_bf16(afr[m], bfr[n], acc[4 + m][n], 0, 0, 0);
      __builtin_amdgcn_s_setprio(0);
      mbar();
    }
    if (t + 2 < T) stage(t + 2, b);
  }

#pragma unroll
  for (int m = 0; m < 8; ++m)
#pragma unroll
    for (int n = 0; n < 4; ++n) {
      const size_t c = col0 + wcol + n * 16 + lo;
      const float bv = bias[c];
#pragma unroll
      for (int i = 0; i < 4; ++i) {
        const size_t r = row0 + wrow + m * 16 + hi * 4 + i;
        C[r * (size_t)N + c] = acc[m][n][i] + bv;
      }
    }
}

// ---------------- chunk attention: attend over nc=4 chunks ----------------
__global__ __launch_bounds__(64)
void chunk_attn(const float* __restrict__ qkv, u16* __restrict__ out) {
  const int p = blockIdx.x, h = blockIdx.y, d = threadIdx.x;
  float q[4], k[4], v[4];
#pragma unroll
  for (int c = 0; c < 4; ++c) {
    const float* b = qkv + (size_t)((c << 10) + p) * 1536 + (h << 6) + d;
    q[c] = b[0]; k[c] = b[512]; v[c] = b[1024];
  }
  float sc[4][4];
#pragma unroll
  for (int i = 0; i < 4; ++i)
#pragma unroll
    for (int j = 0; j < 4; ++j) sc[i][j] = q[i] * k[j];
#pragma unroll
  for (int mask = 1; mask < 64; mask <<= 1)
#pragma unroll
    for (int i = 0; i < 4; ++i)
#pragma unroll
      for (int j = 0; j < 4; ++j) sc[i][j] += __shfl_xor(sc[i][j], mask);
#pragma unroll
  for (int i = 0; i < 4; ++i) {
    float s0 = sc[i][0] * 0.125f, s1 = sc[i][1] * 0.125f,
          s2 = sc[i][2] * 0.125f, s3 = sc[i][3] * 0.125f;
    const float mx = fmaxf(fmaxf(s0, s1), fmaxf(s2, s3));
    const float e0 = __expf(s0 - mx), e1 = __expf(s1 - mx),
                e2 = __expf(s2 - mx), e3 = __expf(s3 - mx);
    const float inv = 1.0f / (e0 + e1 + e2 + e3);
    const float o = (e0 * v[0] + e1 * v[1] + e2 * v[2] + e3 * v[3]) * inv;
    out[(size_t)((i << 10) + p) * 512 + (h << 6) + d] = f2b(o);
  }
}

// ---------------- global flash attention: 128 q-rows/block, 8 waves, T14 prefetch ----------------
__global__ __launch_bounds__(512)
void flash_attn(const u16* __restrict__ qkv, u16* __restrict__ out) {
  __shared__ __align__(16) u16 Ks[64 * 64];
  __shared__ __align__(16) u16 Vt[64 * 64];
  __shared__ __align__(16) u16 Pls[128 * 64];
  const int tid = threadIdx.x, wid = tid >> 6, lane = tid & 63;
  const int lo = lane & 15, hi = lane >> 4;
  const int q0 = blockIdx.x << 7, h = blockIdx.y;
  const int hoff = h << 6;
  char* KsB = (char*)Ks; char* VtB = (char*)Vt; char* PlB = (char*)Pls;

  bf16x8 qf[2];
#pragma unroll
  for (int kh = 0; kh < 2; ++kh)
    qf[kh] = *(const bf16x8*)(qkv + (size_t)(q0 + wid * 16 + lo) * 1536 + hoff + kh * 32 + hi * 8);

  f32x4 o[4] = {};
  float mr[4] = {-3e38f, -3e38f, -3e38f, -3e38f};
  float lr[4] = {0.f, 0.f, 0.f, 0.f};

  const int krow = tid >> 3, kq = tid & 7;   // 64 rows x 8 chunks

  // prefetch tile 0 (T14 async-stage split)
  bf16x8 kpre = *(const bf16x8*)(qkv + (size_t)krow * 1536 + 512 + hoff + kq * 8);
  bf16x8 vpre = *(const bf16x8*)(qkv + (size_t)krow * 1536 + 1024 + hoff + kq * 8);

  for (int kv0 = 0; kv0 < 4096; kv0 += 64) {
    __syncthreads();   // prev tile's LDS consumers done
    *(bf16x8*)(KsB + ((krow * 128 + kq * 16) ^ ((krow & 7) << 4))) = kpre;
#pragma unroll
    for (int dd = 0; dd < 8; ++dd) {
      const int d = kq * 8 + dd;
      *(u16*)(VtB + ((d * 128 + 2 * krow) ^ ((d & 7) << 4))) = (u16)vpre[dd];
    }
    __syncthreads();   // staging visible
    if (kv0 + 64 < 4096) {   // issue next tile's loads; latency hides under compute
      kpre = *(const bf16x8*)(qkv + (size_t)(kv0 + 64 + krow) * 1536 + 512 + hoff + kq * 8);
      vpre = *(const bf16x8*)(qkv + (size_t)(kv0 + 64 + krow) * 1536 + 1024 + hoff + kq * 8);
    }

    // QK^T
    f32x4 s[4] = {};
#pragma unroll
    for (int n = 0; n < 4; ++n) {
      const int key = n * 16 + lo;
#pragma unroll
      for (int kh = 0; kh < 2; ++kh) {
        bf16x8 kf = *(const bf16x8*)(KsB + ((key * 128 + kh * 64 + hi * 16) ^ ((key & 7) << 4)));
        s[n] = __builtin_amdgcn_mfma_f32_16x16x32_bf16(qf[kh], kf, s[n], 0, 0, 0);
      }
      s[n] *= 0.125f;
    }

    // online softmax
    float tmax[4];
#pragma unroll
    for (int i = 0; i < 4; ++i) {
      float t = fmaxf(fmaxf(s[0][i], s[1][i]), fmaxf(s[2][i], s[3][i]));
#pragma unroll
      for (int mask = 1; mask < 16; mask <<= 1) t = fmaxf(t, __shfl_xor(t, mask));
      tmax[i] = t;
    }
    float sc[4], rs[4];
#pragma unroll
    for (int i = 0; i < 4; ++i) {
      const float mn = fmaxf(mr[i], tmax[i]);
      sc[i] = __expf(mr[i] - mn);
      mr[i] = mn;
      rs[i] = 0.f;
    }
    const int prow_base = wid * 16 + hi * 4;
#pragma unroll
    for (int n = 0; n < 4; ++n)
#pragma unroll
      for (int i = 0; i < 4; ++i) {
        const float pv = __expf(s[n][i] - mr[i]);
        rs[i] += pv;
        const int row = prow_base + i;
        *(u16*)(PlB + (((row * 64 + n * 16 + lo) * 2) ^ ((row & 7) << 4))) = f2b(pv);
      }
#pragma unroll
    for (int i = 0; i < 4; ++i) {
#pragma unroll
      for (int mask = 1; mask < 16; mask <<= 1) rs[i] += __shfl_xor(rs[i], mask);
      lr[i] = lr[i] * sc[i] + rs[i];
#pragma unroll
      for (int n = 0; n < 4; ++n) o[n][i] *= sc[i];
    }

    // PV
#pragma unroll
    for (int kh = 0; kh < 2; ++kh) {
      const int prow = wid * 16 + lo;
      bf16x8 pa = *(const bf16x8*)(PlB + ((prow * 128 + kh * 64 + hi * 16) ^ ((lo & 7) << 4)));
#pragma unroll
      for (int n = 0; n < 4; ++n) {
        const int vd = n * 16 + lo;
        bf16x8 vf = *(const bf16x8*)(VtB + ((vd * 128 + kh * 64 + hi * 16) ^ ((vd & 7) << 4)));
        o[n] = __builtin_amdgcn_mfma_f32_16x16x32_bf16(pa, vf, o[n], 0, 0, 0);
      }
    }
  }

#pragma unroll
  for (int n = 0; n < 4; ++n)
#pragma unroll
    for (int i = 0; i < 4; ++i) {
      const int r = q0 + wid * 16 + hi * 4 + i;
      out[(size_t)r * 512 + hoff + n * 16 + lo] = f2b(o[n][i] / lr[i]);
    }
}

// ---------------- residual add + LayerNorm ----------------
__global__ __launch_bounds__(256)
void add_ln(const float* __restrict__ a, const float* __restrict__ b,
            const float* __restrict__ g, const float* __restrict__ be,
            float* __restrict__ of, u16* __restrict__ ob) {
  const int wid = threadIdx.x >> 6, lane = threadIdx.x & 63;
  const int row = blockIdx.x * 4 + wid;
  const size_t base = (size_t)row * 512 + lane * 8;
  float4 a0 = *(const float4*)(a + base), a1 = *(const float4*)(a + base + 4);
  float4 b0 = *(const float4*)(b + base), b1 = *(const float4*)(b + base + 4);
  float x[8] = {a0.x + b0.x, a0.y + b0.y, a0.z + b0.z, a0.w + b0.w,
                a1.x + b1.x, a1.y + b1.y, a1.z + b1.z, a1.w + b1.w};
  float s = 0.f, sq = 0.f;
#pragma unroll
  for (int j = 0; j < 8; ++j) { s += x[j]; sq += x[j] * x[j]; }
#pragma unroll
  for (int mask = 1; mask < 64; mask <<= 1) {
    s += __shfl_xor(s, mask);
    sq += __shfl_xor(sq, mask);
  }
  const float mean = s * (1.0f / 512.0f);
  const float var = sq * (1.0f / 512.0f) - mean * mean;
  const float rstd = rsqrtf(var + 1e-5f);
  float4 g0 = *(const float4*)(g + lane * 8), g1 = *(const float4*)(g + lane * 8 + 4);
  float4 e0 = *(const float4*)(be + lane * 8), e1 = *(const float4*)(be + lane * 8 + 4);
  const float gg[8] = {g0.x, g0.y, g0.z, g0.w, g1.x, g1.y, g1.z, g1.w};
  const float bb[8] = {e0.x, e0.y, e0.z, e0.w, e1.x, e1.y, e1.z, e1.w};
#pragma unroll
  for (int j = 0; j < 8; ++j) {
    const float y = (x[j] - mean) * rstd * gg[j] + bb[j];
    of[base + j] = y;
    ob[base + j] = f2b(y);
  }
}

extern "C" void kernel_launch(void* const* d_in, const int* in_sizes, int n_in,
                              void* d_out, int out_size, void* d_ws, size_t ws_size,
                              hipStream_t stream) {
  (void)in_sizes; (void)n_in; (void)out_size; (void)ws_size;
  const int*   tokens = (const int*)d_in[0];
  const float* emb    = (const float*)d_in[1];
  const float* cwin   = (const float*)d_in[2];
  const float* cbin   = (const float*)d_in[3];
  const float* cwout  = (const float*)d_in[4];
  const float* cbout  = (const float*)d_in[5];
  const float* gwin   = (const float*)d_in[6];
  const float* gbin   = (const float*)d_in[7];
  const float* gwout  = (const float*)d_in[8];
  const float* gbout  = (const float*)d_in[9];
  const float* ln1g   = (const float*)d_in[10];
  const float* ln1b   = (const float*)d_in[11];
  const float* fw1    = (const float*)d_in[12];
  const float* fb1    = (const float*)d_in[13];
  const float* fw2    = (const float*)d_in[14];
  const float* fb2    = (const float*)d_in[15];
  const float* ln2g   = (const float*)d_in[16];
  const float* ln2b   = (const float*)d_in[17];
  const float* fcw    = (const float*)d_in[18];
  const float* fcb    = (const float*)d_in[19];
  float* out = (float*)d_out;

  char* ws = (char*)d_ws;
  size_t off = 0;
  auto alloc = [&](size_t bytes) -> void* {
    void* p = ws + off;
    off += (bytes + 255) & ~(size_t)255;
    return p;
  };
  u16*   xb   = (u16*)alloc((size_t)4096 * 512 * 2);
  float* xf   = (float*)alloc((size_t)4096 * 512 * 4);
  float* qkv1 = (float*)alloc((size_t)4096 * 1536 * 4);
  u16*   at1  = (u16*)alloc((size_t)4096 * 512 * 2);
  u16*   cab  = (u16*)alloc((size_t)4096 * 512 * 2);
  u16*   qkv2 = (u16*)alloc((size_t)4096 * 1536 * 2);
  u16*   at2  = (u16*)alloc((size_t)4096 * 512 * 2);
  float* gaf  = (float*)alloc((size_t)4096 * 512 * 4);
  float* x1f  = (float*)alloc((size_t)4096 * 512 * 4);
  u16*   x1b  = (u16*)alloc((size_t)4096 * 512 * 2);
  u16*   f1b  = (u16*)alloc((size_t)4096 * 2048 * 2);
  float* ff   = (float*)alloc((size_t)4096 * 512 * 4);
  float* x2f  = (float*)alloc((size_t)4096 * 512 * 4);
  u16*   x2b  = (u16*)alloc((size_t)4096 * 512 * 2);
  u16*   wcinb  = (u16*)alloc((size_t)1536 * 512 * 2);
  u16*   wcoutb = (u16*)alloc((size_t)512 * 512 * 2);
  u16*   wginb  = (u16*)alloc((size_t)1536 * 512 * 2);
  u16*   wgoutb = (u16*)alloc((size_t)512 * 512 * 2);
  u16*   wf1b   = (u16*)alloc((size_t)2048 * 512 * 2);
  u16*   wf2b   = (u16*)alloc((size_t)512 * 2048 * 2);
  u16*   wfcb   = (u16*)alloc((size_t)32000 * 512 * 2);

  // all weight conversions in one launch
  f2b_multi<<<2048, 256, 0, stream>>>(
      (const float4*)cwin, wcinb, (const float4*)cwout, wcoutb,
      (const float4*)gwin, wginb, (const float4*)gwout, wgoutb,
      (const float4*)fw1, wf1b, (const float4*)fw2, wf2b,
      (const float4*)fcw, wfcb);

  embed_pe<<<4096, 256, 0, stream>>>(tokens, emb, xf, xb);

  // chunk stage
  gemm_bt<0, 1, 0><<<384, 256, 0, stream>>>(xb, wcinb, cbin, qkv1, (u16*)nullptr, 4096, 1536, 512);
  chunk_attn<<<dim3(1024, 8), 64, 0, stream>>>(qkv1, at1);
  gemm_bt<0, 0, 1><<<128, 256, 0, stream>>>(at1, wcoutb, cbout, (float*)nullptr, cab, 4096, 512, 512);

  // global stage
  gemm_bt<0, 0, 1><<<384, 256, 0, stream>>>(cab, wginb, gbin, (float*)nullptr, qkv2, 4096, 1536, 512);
  flash_attn<<<dim3(32, 8), 512, 0, stream>>>(qkv2, at2);
  gemm_bt<0, 1, 0><<<128, 256, 0, stream>>>(at2, wgoutb, gbout, gaf, (u16*)nullptr, 4096, 512, 512);

  // post-norm encoder layer
  add_ln<<<1024, 256, 0, stream>>>(xf, gaf, ln1g, ln1b, x1f, x1b);
  gemm_bt<1, 0, 1><<<512, 256, 0, stream>>>(x1b, wf1b, fb1, (float*)nullptr, f1b, 4096, 2048, 512);
  gemm_bt<0, 1, 0><<<128, 256, 0, stream>>>(f1b, wf2b, fb2, ff, (u16*)nullptr, 4096, 512, 2048);
  add_ln<<<1024, 256, 0, stream>>>(x1f, ff, ln2g, ln2b, x2f, x2b);

  // vocab projection: 256^2 8-phase pipeline
  gemm256<512><<<2000, 512, 0, stream>>>(x2b, wfcb, fcb, out, 4096, 32000);
}

// Round 3
// 483.982 us; speedup vs baseline: 1.2228x; 1.1294x over previous
//
#include <hip/hip_runtime.h>

typedef __attribute__((ext_vector_type(8))) short bf16x8;
typedef __attribute__((ext_vector_type(4))) float f32x4;
typedef unsigned short u16;

__device__ __forceinline__ u16 f2b(float f) {
  union { float f; unsigned u; } v; v.f = f;
  return (u16)((v.u + 0x7FFFu + ((v.u >> 16) & 1u)) >> 16);
}
__device__ __forceinline__ float b2f(u16 x) {
  union { unsigned u; float f; } v; v.u = (unsigned)x << 16; return v.f;
}

__device__ __forceinline__ void gload16(const void* g, void* l) {
  __builtin_amdgcn_global_load_lds((__attribute__((address_space(1))) void*)(g),
                                   (__attribute__((address_space(3))) void*)(l),
                                   16, 0, 0);
}

__device__ __forceinline__ void mbar() {
  asm volatile("" ::: "memory");
  __builtin_amdgcn_s_barrier();
  asm volatile("" ::: "memory");
}

// ---------------- batched fp32 -> bf16 (all 7 weight tensors, one launch) ----------------
__device__ __forceinline__ void cv1(const float4* __restrict__ s, u16* __restrict__ d, int i) {
  float4 v = s[i];
  unsigned long long pk = (unsigned long long)f2b(v.x) |
                          ((unsigned long long)f2b(v.y) << 16) |
                          ((unsigned long long)f2b(v.z) << 32) |
                          ((unsigned long long)f2b(v.w) << 48);
  *(unsigned long long*)(d + (size_t)i * 4) = pk;
}

__global__ __launch_bounds__(256)
void f2b_multi(const float4* s0, u16* d0, const float4* s1, u16* d1,
               const float4* s2, u16* d2, const float4* s3, u16* d3,
               const float4* s4, u16* d4, const float4* s5, u16* d5,
               const float4* s6, u16* d6) {
  int i = blockIdx.x * 256 + threadIdx.x;
  const int stride = gridDim.x * 256;
  for (; i < 5144576; i += stride) {
    int j = i;
    if (j < 196608) { cv1(s0, d0, j); continue; }
    j -= 196608;
    if (j < 65536) { cv1(s1, d1, j); continue; }
    j -= 65536;
    if (j < 196608) { cv1(s2, d2, j); continue; }
    j -= 196608;
    if (j < 65536) { cv1(s3, d3, j); continue; }
    j -= 65536;
    if (j < 262144) { cv1(s4, d4, j); continue; }
    j -= 262144;
    if (j < 262144) { cv1(s5, d5, j); continue; }
    j -= 262144;
    cv1(s6, d6, j);
  }
}

// ---------------- embedding * sqrt(D) + sinusoidal PE ----------------
__global__ __launch_bounds__(256) void embed_pe(const int* __restrict__ tok,
    const float* __restrict__ emb, float* __restrict__ xf, u16* __restrict__ xb) {
  const int s = blockIdx.x;
  const int i = threadIdx.x;
  const int t = tok[s];
  const float div = __expf((float)(2 * i) * -0.017988946039015984f);
  const float ang = (float)s * div;
  const float sv = sinf(ang), cv = cosf(ang);
  const float* e = emb + (size_t)t * 512 + 2 * i;
  const float x0 = e[0] * 22.627416997969522f + sv;
  const float x1 = e[1] * 22.627416997969522f + cv;
  const size_t o = (size_t)s * 512 + 2 * i;
  xf[o] = x0; xf[o + 1] = x1;
  xb[o] = f2b(x0); xb[o + 1] = f2b(x1);
}

// ---------------- tiled GEMM: C = A(MxK) . B(NxK)^T + bias; BM in {64,128} ----------------
template<int BM, int RELU, int WF32, int WB16>
__global__ __launch_bounds__(256)
void gemm_bt(const u16* __restrict__ A, const u16* __restrict__ B,
             const float* __restrict__ bias, float* __restrict__ Cf,
             u16* __restrict__ Cb, int M, int N, int K)
{
  constexpr int MFR = BM / 32;            // m-frags per wave
  __shared__ __align__(16) u16 As[BM * 32];
  __shared__ __align__(16) u16 Bs[128 * 32];
  const int tid = threadIdx.x;
  const int wid = tid >> 6, lane = tid & 63;
  const int lo = lane & 15, hi = lane >> 4;
  const int nbn = N >> 7;
  const int cpx = (int)gridDim.x >> 3;
  const int bid = blockIdx.x;
  const int swz = (bid & 7) * cpx + (bid >> 3);
  const int bi = swz / nbn, bj = swz - bi * nbn;
  const size_t row0 = (size_t)bi * BM, col0 = (size_t)bj << 7;
  const int wr = (wid >> 1) * (BM / 2), wc = (wid & 1) << 6;
  const int r0 = (wid << 5) + (lane >> 2);   // B staging row (and A for BM=128)
  const int c0 = (lane & 3) << 3;
  const int ra = tid >> 2, ca = (tid & 3) << 3;  // A staging for BM=64

  f32x4 acc[MFR][4] = {};

  for (int k0 = 0; k0 < K; k0 += 32) {
    __syncthreads();
    if constexpr (BM == 128) {
      gload16(A + (row0 + r0) * (size_t)K + k0 + c0,      &As[wid * 1024]);
      gload16(A + (row0 + r0 + 16) * (size_t)K + k0 + c0, &As[wid * 1024 + 512]);
    } else {
      gload16(A + (row0 + ra) * (size_t)K + k0 + ca,      &As[wid * 512]);
    }
    gload16(B + (col0 + r0) * (size_t)K + k0 + c0,      &Bs[wid * 1024]);
    gload16(B + (col0 + r0 + 16) * (size_t)K + k0 + c0, &Bs[wid * 1024 + 512]);
    __syncthreads();
    bf16x8 af[MFR], bfr[4];
#pragma unroll
    for (int m = 0; m < MFR; ++m)
      af[m] = *(const bf16x8*)&As[(wr + m * 16 + lo) * 32 + hi * 8];
#pragma unroll
    for (int n = 0; n < 4; ++n)
      bfr[n] = *(const bf16x8*)&Bs[(wc + n * 16 + lo) * 32 + hi * 8];
#pragma unroll
    for (int m = 0; m < MFR; ++m)
#pragma unroll
      for (int n = 0; n < 4; ++n)
        acc[m][n] = __builtin_amdgcn_mfma_f32_16x16x32_bf16(af[m], bfr[n], acc[m][n], 0, 0, 0);
  }

#pragma unroll
  for (int m = 0; m < MFR; ++m)
#pragma unroll
    for (int n = 0; n < 4; ++n) {
      const size_t c = col0 + wc + n * 16 + lo;
      const float bv = bias[c];
#pragma unroll
      for (int i = 0; i < 4; ++i) {
        const size_t r = row0 + wr + m * 16 + hi * 4 + i;
        float v = acc[m][n][i] + bv;
        if (RELU) v = fmaxf(v, 0.0f);
        if (WF32) Cf[r * (size_t)N + c] = v;
        if (WB16) Cb[r * (size_t)N + c] = f2b(v);
      }
    }
}

// ---------------- 256x256 8-phase GEMM (FC projection) ----------------
template<int KC>
__global__ __launch_bounds__(512, 2)
void gemm256(const u16* __restrict__ A, const u16* __restrict__ B,
             const float* __restrict__ bias, float* __restrict__ C,
             int M, int N)
{
  constexpr int T = KC / 64;
  __shared__ __align__(16) u16 LA[2][256 * 64];
  __shared__ __align__(16) u16 LB[2][256 * 64];
  const int tid = threadIdx.x;
  const int wid = tid >> 6, lane = tid & 63;
  const int lo = lane & 15, hi = lane >> 4;
  const int nbn = N >> 8;
  const int cpx = (int)gridDim.x >> 3;
  const int bid = blockIdx.x;
  const int swz = (bid & 7) * cpx + (bid >> 3);
  const int bi = swz / nbn, bj = swz - bi * nbn;
  const size_t row0 = (size_t)bi << 8, col0 = (size_t)bj << 8;
  const int wrow = (wid >> 2) << 7;
  const int wcol = (wid & 3) << 6;

  const int srow = (wid << 3) + (lane >> 3);
  const int scol = ((lane & 7) ^ (lane >> 3)) << 3;
  const u16* srcA = A + (row0 + srow) * (size_t)KC + scol;
  const u16* srcB = B + (col0 + srow) * (size_t)KC + scol;
  const int ldst = wid << 9;

  f32x4 acc[8][4] = {};

  auto stage = [&](int t, int b) {
    const size_t ko = (size_t)t * 64;
#pragma unroll
    for (int i = 0; i < 4; ++i)
      gload16(srcA + ko + (size_t)(i * 64) * KC, &LA[b][ldst + i * 4096]);
#pragma unroll
    for (int i = 0; i < 4; ++i)
      gload16(srcB + ko + (size_t)(i * 64) * KC, &LB[b][ldst + i * 4096]);
  };

  auto rd = [&](const u16* base, int row, int ks) -> bf16x8 {
    const int byte = row * 128 + ((((ks << 2) | hi) ^ (row & 7)) << 4);
    return *(const bf16x8*)((const char*)base + byte);
  };

  stage(0, 0);
  stage(1, 1);

  for (int t = 0; t < T; ++t) {
    const int b = t & 1;
    const u16* Ab = LA[b];
    const u16* Bb = LB[b];
    if (t + 1 < T) { asm volatile("s_waitcnt vmcnt(8)" ::: "memory"); }
    else           { asm volatile("s_waitcnt vmcnt(0)" ::: "memory"); }
    __builtin_amdgcn_sched_barrier(0);
    mbar();

    bf16x8 afr[4], bfr[4];
#pragma unroll
    for (int ks = 0; ks < 2; ++ks) {
#pragma unroll
      for (int m = 0; m < 4; ++m) afr[m] = rd(Ab, wrow + m * 16 + lo, ks);
#pragma unroll
      for (int n = 0; n < 4; ++n) bfr[n] = rd(Bb, wcol + n * 16 + lo, ks);
      mbar();
      asm volatile("s_waitcnt lgkmcnt(0)" ::: "memory");
      __builtin_amdgcn_sched_barrier(0);
      __builtin_amdgcn_s_setprio(1);
#pragma unroll
      for (int m = 0; m < 4; ++m)
#pragma unroll
        for (int n = 0; n < 4; ++n)
          acc[m][n] = __builtin_amdgcn_mfma_f32_16x16x32_bf16(afr[m], bfr[n], acc[m][n], 0, 0, 0);
      __builtin_amdgcn_s_setprio(0);
      mbar();
#pragma unroll
      for (int m = 0; m < 4; ++m) afr[m] = rd(Ab, wrow + (4 + m) * 16 + lo, ks);
      mbar();
      asm volatile("s_waitcnt lgkmcnt(0)" ::: "memory");
      __builtin_amdgcn_sched_barrier(0);
      __builtin_amdgcn_s_setprio(1);
#pragma unroll
      for (int m = 0; m < 4; ++m)
#pragma unroll
        for (int n = 0; n < 4; ++n)
          acc[4 + m][n] = __builtin_amdgcn_mfma_f32_16x16x32_bf16(afr[m], bfr[n], acc[4 + m][n], 0, 0, 0);
      __builtin_amdgcn_s_setprio(0);
      mbar();
    }
    if (t + 2 < T) stage(t + 2, b);   // must stay post-compute: writes buffer b (tile t's)
  }

#pragma unroll
  for (int m = 0; m < 8; ++m)
#pragma unroll
    for (int n = 0; n < 4; ++n) {
      const size_t c = col0 + wcol + n * 16 + lo;
      const float bv = bias[c];
#pragma unroll
      for (int i = 0; i < 4; ++i) {
        const size_t r = row0 + wrow + m * 16 + hi * 4 + i;
        C[r * (size_t)N + c] = acc[m][n][i] + bv;
      }
    }
}

// ---------------- chunk attention: attend over nc=4 chunks (bf16 qkv) ----------------
__global__ __launch_bounds__(64)
void chunk_attn(const u16* __restrict__ qkv, u16* __restrict__ out) {
  const int p = blockIdx.x, h = blockIdx.y, d = threadIdx.x;
  float q[4], k[4], v[4];
#pragma unroll
  for (int c = 0; c < 4; ++c) {
    const u16* b = qkv + (size_t)((c << 10) + p) * 1536 + (h << 6) + d;
    q[c] = b2f(b[0]); k[c] = b2f(b[512]); v[c] = b2f(b[1024]);
  }
  float sc[4][4];
#pragma unroll
  for (int i = 0; i < 4; ++i)
#pragma unroll
    for (int j = 0; j < 4; ++j) sc[i][j] = q[i] * k[j];
#pragma unroll
  for (int mask = 1; mask < 64; mask <<= 1)
#pragma unroll
    for (int i = 0; i < 4; ++i)
#pragma unroll
      for (int j = 0; j < 4; ++j) sc[i][j] += __shfl_xor(sc[i][j], mask);
#pragma unroll
  for (int i = 0; i < 4; ++i) {
    float s0 = sc[i][0] * 0.125f, s1 = sc[i][1] * 0.125f,
          s2 = sc[i][2] * 0.125f, s3 = sc[i][3] * 0.125f;
    const float mx = fmaxf(fmaxf(s0, s1), fmaxf(s2, s3));
    const float e0 = __expf(s0 - mx), e1 = __expf(s1 - mx),
                e2 = __expf(s2 - mx), e3 = __expf(s3 - mx);
    const float inv = 1.0f / (e0 + e1 + e2 + e3);
    const float o = (e0 * v[0] + e1 * v[1] + e2 * v[2] + e3 * v[3]) * inv;
    out[(size_t)((i << 10) + p) * 512 + (h << 6) + d] = f2b(o);
  }
}

// ---------------- global flash attention: swapped QK^T, in-lane softmax ----------------
// 8 waves x 16 q-rows; KV tiles of 64; S^T = mfma(K,Q) so q = lane&15 (softmax in-lane)
__global__ __launch_bounds__(512)
void flash_attn(const u16* __restrict__ qkv, u16* __restrict__ out) {
  __shared__ __align__(16) u16 Ks[64 * 64];
  __shared__ __align__(16) u16 Vt[64 * 64];
  __shared__ __align__(16) u16 Pp[8][16 * 64];   // wave-private P, swizzled [q_lo][k]
  const int tid = threadIdx.x, wid = tid >> 6, lane = tid & 63;
  const int lo = lane & 15, hi = lane >> 4;
  const int q0 = blockIdx.x << 7, h = blockIdx.y;
  const int hoff = h << 6;
  char* KsB = (char*)Ks; char* VtB = (char*)Vt;
  char* Pw = (char*)&Pp[wid][0];
  const int xsw = (lo & 7) << 4;

  // Q fragments (B-operand: col=q=lo, k-slice hi*8) — same layout as a row-load
  bf16x8 qf[2];
#pragma unroll
  for (int kh = 0; kh < 2; ++kh)
    qf[kh] = *(const bf16x8*)(qkv + (size_t)(q0 + wid * 16 + lo) * 1536 + hoff + kh * 32 + hi * 8);

  f32x4 o[4] = {};
  float mr = -3e38f, lr = 0.f;     // per-lane online-softmax state for q = lo

  const int krow = tid >> 3, kq = tid & 7;

  bf16x8 kpre = *(const bf16x8*)(qkv + (size_t)krow * 1536 + 512 + hoff + kq * 8);
  bf16x8 vpre = *(const bf16x8*)(qkv + (size_t)krow * 1536 + 1024 + hoff + kq * 8);

  for (int kv0 = 0; kv0 < 4096; kv0 += 64) {
    __syncthreads();
    *(bf16x8*)(KsB + ((krow * 128 + kq * 16) ^ ((krow & 7) << 4))) = kpre;
#pragma unroll
    for (int dd = 0; dd < 8; ++dd) {
      const int d = kq * 8 + dd;
      *(u16*)(VtB + ((d * 128 + 2 * krow) ^ ((d & 7) << 4))) = (u16)vpre[dd];
    }
    __syncthreads();
    if (kv0 + 64 < 4096) {
      kpre = *(const bf16x8*)(qkv + (size_t)(kv0 + 64 + krow) * 1536 + 512 + hoff + kq * 8);
      vpre = *(const bf16x8*)(qkv + (size_t)(kv0 + 64 + krow) * 1536 + 1024 + hoff + kq * 8);
    }

    // S^T[n]: rows = keys n*16 + hi*4 + i, col = q = lo   (A = K-frag, B = Q-frag)
    f32x4 s[4] = {};
#pragma unroll
    for (int n = 0; n < 4; ++n) {
      const int key = n * 16 + lo;
#pragma unroll
      for (int kh = 0; kh < 2; ++kh) {
        bf16x8 kf = *(const bf16x8*)(KsB + ((key * 128 + kh * 64 + hi * 16) ^ ((key & 7) << 4)));
        s[n] = __builtin_amdgcn_mfma_f32_16x16x32_bf16(kf, qf[kh], s[n], 0, 0, 0);
      }
      s[n] *= 0.125f;
    }

    // per-lane max over this lane's 16 keys, then combine the 4 hi-groups
    float pm = s[0][0];
#pragma unroll
    for (int n = 0; n < 4; ++n)
#pragma unroll
      for (int i = 0; i < 4; ++i) pm = fmaxf(pm, s[n][i]);
    pm = fmaxf(pm, __shfl_xor(pm, 16));
    pm = fmaxf(pm, __shfl_xor(pm, 32));

    if (__any(pm > mr + 8.f)) {          // defer-max (T13): rescale only when needed
      const float mn = fmaxf(mr, pm);
      const float sc = __expf(mr - mn);
      mr = mn;
      lr *= sc;
#pragma unroll
      for (int i = 0; i < 4; ++i) {
        const float sq = __shfl(sc, hi * 4 + i);   // o rows are q = hi*4+i
#pragma unroll
        for (int n = 0; n < 4; ++n) o[n][i] *= sq;
      }
    }

    // P = exp(S - m); pack pairs to bf16; wave-private LDS write (4 x b64)
    float rs = 0.f;
    unsigned U[8];
#pragma unroll
    for (int n = 0; n < 4; ++n) {
      const float p0 = __expf(s[n][0] - mr);
      const float p1 = __expf(s[n][1] - mr);
      const float p2 = __expf(s[n][2] - mr);
      const float p3 = __expf(s[n][3] - mr);
      rs += (p0 + p1) + (p2 + p3);
      asm("v_cvt_pk_bf16_f32 %0, %1, %2" : "=v"(U[2 * n])     : "v"(p0), "v"(p1));
      asm("v_cvt_pk_bf16_f32 %0, %1, %2" : "=v"(U[2 * n + 1]) : "v"(p2), "v"(p3));
    }
    rs += __shfl_xor(rs, 16);
    rs += __shfl_xor(rs, 32);
    lr += rs;
#pragma unroll
    for (int n = 0; n < 4; ++n) {
      const int off = lo * 128 + ((n * 32 + hi * 8) ^ xsw);  // [q=lo][k=16n+4hi..+3]
      const unsigned long long dw = (unsigned long long)U[2 * n] |
                                    ((unsigned long long)U[2 * n + 1] << 32);
      *(unsigned long long*)(Pw + off) = dw;
    }

    // PV: A = P (row=q=lo, k-slice kh*32+hi*8), B = V^T frags
#pragma unroll
    for (int kh = 0; kh < 2; ++kh) {
      bf16x8 pa = *(const bf16x8*)(Pw + lo * 128 + ((kh * 64 + hi * 16) ^ xsw));
#pragma unroll
      for (int n = 0; n < 4; ++n) {
        const int vd = n * 16 + lo;
        bf16x8 vf = *(const bf16x8*)(VtB + ((vd * 128 + kh * 64 + hi * 16) ^ ((vd & 7) << 4)));
        o[n] = __builtin_amdgcn_mfma_f32_16x16x32_bf16(pa, vf, o[n], 0, 0, 0);
      }
    }
  }

#pragma unroll
  for (int i = 0; i < 4; ++i) {
    const float lq = __shfl(lr, hi * 4 + i);
    const float inv = 1.0f / lq;
    const int r = q0 + wid * 16 + hi * 4 + i;
#pragma unroll
    for (int n = 0; n < 4; ++n)
      out[(size_t)r * 512 + hoff + n * 16 + lo] = f2b(o[n][i] * inv);
  }
}

// ---------------- residual add + LayerNorm ----------------
__global__ __launch_bounds__(256)
void add_ln(const float* __restrict__ a, const float* __restrict__ b,
            const float* __restrict__ g, const float* __restrict__ be,
            float* __restrict__ of, u16* __restrict__ ob) {
  const int wid = threadIdx.x >> 6, lane = threadIdx.x & 63;
  const int row = blockIdx.x * 4 + wid;
  const size_t base = (size_t)row * 512 + lane * 8;
  float4 a0 = *(const float4*)(a + base), a1 = *(const float4*)(a + base + 4);
  float4 b0 = *(const float4*)(b + base), b1 = *(const float4*)(b + base + 4);
  float x[8] = {a0.x + b0.x, a0.y + b0.y, a0.z + b0.z, a0.w + b0.w,
                a1.x + b1.x, a1.y + b1.y, a1.z + b1.z, a1.w + b1.w};
  float s = 0.f, sq = 0.f;
#pragma unroll
  for (int j = 0; j < 8; ++j) { s += x[j]; sq += x[j] * x[j]; }
#pragma unroll
  for (int mask = 1; mask < 64; mask <<= 1) {
    s += __shfl_xor(s, mask);
    sq += __shfl_xor(sq, mask);
  }
  const float mean = s * (1.0f / 512.0f);
  const float var = sq * (1.0f / 512.0f) - mean * mean;
  const float rstd = rsqrtf(var + 1e-5f);
  float4 g0 = *(const float4*)(g + lane * 8), g1 = *(const float4*)(g + lane * 8 + 4);
  float4 e0 = *(const float4*)(be + lane * 8), e1 = *(const float4*)(be + lane * 8 + 4);
  const float gg[8] = {g0.x, g0.y, g0.z, g0.w, g1.x, g1.y, g1.z, g1.w};
  const float bb[8] = {e0.x, e0.y, e0.z, e0.w, e1.x, e1.y, e1.z, e1.w};
#pragma unroll
  for (int j = 0; j < 8; ++j) {
    const float y = (x[j] - mean) * rstd * gg[j] + bb[j];
    of[base + j] = y;
    ob[base + j] = f2b(y);
  }
}

extern "C" void kernel_launch(void* const* d_in, const int* in_sizes, int n_in,
                              void* d_out, int out_size, void* d_ws, size_t ws_size,
                              hipStream_t stream) {
  (void)in_sizes; (void)n_in; (void)out_size; (void)ws_size;
  const int*   tokens = (const int*)d_in[0];
  const float* emb    = (const float*)d_in[1];
  const float* cwin   = (const float*)d_in[2];
  const float* cbin   = (const float*)d_in[3];
  const float* cwout  = (const float*)d_in[4];
  const float* cbout  = (const float*)d_in[5];
  const float* gwin   = (const float*)d_in[6];
  const float* gbin   = (const float*)d_in[7];
  const float* gwout  = (const float*)d_in[8];
  const float* gbout  = (const float*)d_in[9];
  const float* ln1g   = (const float*)d_in[10];
  const float* ln1b   = (const float*)d_in[11];
  const float* fw1    = (const float*)d_in[12];
  const float* fb1    = (const float*)d_in[13];
  const float* fw2    = (const float*)d_in[14];
  const float* fb2    = (const float*)d_in[15];
  const float* ln2g   = (const float*)d_in[16];
  const float* ln2b   = (const float*)d_in[17];
  const float* fcw    = (const float*)d_in[18];
  const float* fcb    = (const float*)d_in[19];
  float* out = (float*)d_out;

  char* ws = (char*)d_ws;
  size_t off = 0;
  auto alloc = [&](size_t bytes) -> void* {
    void* p = ws + off;
    off += (bytes + 255) & ~(size_t)255;
    return p;
  };
  u16*   xb    = (u16*)alloc((size_t)4096 * 512 * 2);
  float* xf    = (float*)alloc((size_t)4096 * 512 * 4);
  u16*   qkv1b = (u16*)alloc((size_t)4096 * 1536 * 2);
  u16*   at1   = (u16*)alloc((size_t)4096 * 512 * 2);
  u16*   cab   = (u16*)alloc((size_t)4096 * 512 * 2);
  u16*   qkv2  = (u16*)alloc((size_t)4096 * 1536 * 2);
  u16*   at2   = (u16*)alloc((size_t)4096 * 512 * 2);
  float* gaf   = (float*)alloc((size_t)4096 * 512 * 4);
  float* x1f   = (float*)alloc((size_t)4096 * 512 * 4);
  u16*   x1b   = (u16*)alloc((size_t)4096 * 512 * 2);
  u16*   f1b   = (u16*)alloc((size_t)4096 * 2048 * 2);
  float* ff    = (float*)alloc((size_t)4096 * 512 * 4);
  float* x2f   = (float*)alloc((size_t)4096 * 512 * 4);
  u16*   x2b   = (u16*)alloc((size_t)4096 * 512 * 2);
  u16*   wcinb  = (u16*)alloc((size_t)1536 * 512 * 2);
  u16*   wcoutb = (u16*)alloc((size_t)512 * 512 * 2);
  u16*   wginb  = (u16*)alloc((size_t)1536 * 512 * 2);
  u16*   wgoutb = (u16*)alloc((size_t)512 * 512 * 2);
  u16*   wf1b   = (u16*)alloc((size_t)2048 * 512 * 2);
  u16*   wf2b   = (u16*)alloc((size_t)512 * 2048 * 2);
  u16*   wfcb   = (u16*)alloc((size_t)32000 * 512 * 2);

  f2b_multi<<<2048, 256, 0, stream>>>(
      (const float4*)cwin, wcinb, (const float4*)cwout, wcoutb,
      (const float4*)gwin, wginb, (const float4*)gwout, wgoutb,
      (const float4*)fw1, wf1b, (const float4*)fw2, wf2b,
      (const float4*)fcw, wfcb);

  embed_pe<<<4096, 256, 0, stream>>>(tokens, emb, xf, xb);

  // chunk stage
  gemm_bt<128, 0, 0, 1><<<384, 256, 0, stream>>>(xb, wcinb, cbin, (float*)nullptr, qkv1b, 4096, 1536, 512);
  chunk_attn<<<dim3(1024, 8), 64, 0, stream>>>(qkv1b, at1);
  gemm_bt<64, 0, 0, 1><<<256, 256, 0, stream>>>(at1, wcoutb, cbout, (float*)nullptr, cab, 4096, 512, 512);

  // global stage
  gemm_bt<128, 0, 0, 1><<<384, 256, 0, stream>>>(cab, wginb, gbin, (float*)nullptr, qkv2, 4096, 1536, 512);
  flash_attn<<<dim3(32, 8), 512, 0, stream>>>(qkv2, at2);
  gemm_bt<64, 0, 1, 0><<<256, 256, 0, stream>>>(at2, wgoutb, gbout, gaf, (u16*)nullptr, 4096, 512, 512);

  // post-norm encoder layer
  add_ln<<<1024, 256, 0, stream>>>(xf, gaf, ln1g, ln1b, x1f, x1b);
  gemm_bt<128, 1, 0, 1><<<512, 256, 0, stream>>>(x1b, wf1b, fb1, (float*)nullptr, f1b, 4096, 2048, 512);
  gemm_bt<64, 0, 1, 0><<<256, 256, 0, stream>>>(f1b, wf2b, fb2, ff, (u16*)nullptr, 4096, 512, 2048);
  add_ln<<<1024, 256, 0, stream>>>(x1f, ff, ln2g, ln2b, x2f, x2b);

  // vocab projection
  gemm256<512><<<2000, 512, 0, stream>>>(x2b, wfcb, fcb, out, 4096, 32000);
}

// Round 4
// 474.084 us; speedup vs baseline: 1.2483x; 1.0209x over previous
//
#include <hip/hip_runtime.h>

typedef __attribute__((ext_vector_type(8))) short bf16x8;
typedef __attribute__((ext_vector_type(4))) float f32x4;
typedef unsigned short u16;

__device__ __forceinline__ u16 f2b(float f) {
  union { float f; unsigned u; } v; v.f = f;
  return (u16)((v.u + 0x7FFFu + ((v.u >> 16) & 1u)) >> 16);
}
__device__ __forceinline__ float b2f(u16 x) {
  union { unsigned u; float f; } v; v.u = (unsigned)x << 16; return v.f;
}

__device__ __forceinline__ void gload16(const void* g, void* l) {
  __builtin_amdgcn_global_load_lds((__attribute__((address_space(1))) void*)(g),
                                   (__attribute__((address_space(3))) void*)(l),
                                   16, 0, 0);
}

__device__ __forceinline__ void mbar() {
  asm volatile("" ::: "memory");
  __builtin_amdgcn_s_barrier();
  asm volatile("" ::: "memory");
}

// ---------------- batched fp32 -> bf16 (all 7 weight tensors, one launch) ----------------
__device__ __forceinline__ void cv1(const float4* __restrict__ s, u16* __restrict__ d, int i) {
  float4 v = s[i];
  unsigned long long pk = (unsigned long long)f2b(v.x) |
                          ((unsigned long long)f2b(v.y) << 16) |
                          ((unsigned long long)f2b(v.z) << 32) |
                          ((unsigned long long)f2b(v.w) << 48);
  *(unsigned long long*)(d + (size_t)i * 4) = pk;
}

__global__ __launch_bounds__(256)
void f2b_multi(const float4* s0, u16* d0, const float4* s1, u16* d1,
               const float4* s2, u16* d2, const float4* s3, u16* d3,
               const float4* s4, u16* d4, const float4* s5, u16* d5,
               const float4* s6, u16* d6) {
  int i = blockIdx.x * 256 + threadIdx.x;
  const int stride = gridDim.x * 256;
  for (; i < 5144576; i += stride) {
    int j = i;
    if (j < 196608) { cv1(s0, d0, j); continue; }
    j -= 196608;
    if (j < 65536) { cv1(s1, d1, j); continue; }
    j -= 65536;
    if (j < 196608) { cv1(s2, d2, j); continue; }
    j -= 196608;
    if (j < 65536) { cv1(s3, d3, j); continue; }
    j -= 65536;
    if (j < 262144) { cv1(s4, d4, j); continue; }
    j -= 262144;
    if (j < 262144) { cv1(s5, d5, j); continue; }
    j -= 262144;
    cv1(s6, d6, j);
  }
}

// ---------------- embedding * sqrt(D) + sinusoidal PE ----------------
__global__ __launch_bounds__(256) void embed_pe(const int* __restrict__ tok,
    const float* __restrict__ emb, float* __restrict__ xf, u16* __restrict__ xb) {
  const int s = blockIdx.x;
  const int i = threadIdx.x;
  const int t = tok[s];
  const float div = __expf((float)(2 * i) * -0.017988946039015984f);
  const float ang = (float)s * div;
  const float sv = sinf(ang), cv = cosf(ang);
  const float* e = emb + (size_t)t * 512 + 2 * i;
  const float x0 = e[0] * 22.627416997969522f + sv;
  const float x1 = e[1] * 22.627416997969522f + cv;
  const size_t o = (size_t)s * 512 + 2 * i;
  xf[o] = x0; xf[o + 1] = x1;
  xb[o] = f2b(x0); xb[o + 1] = f2b(x1);
}

// ---------------- tiled GEMM: C = A(MxK) . B(NxK)^T + bias; BK=64, swizzled LDS ----------------
template<int BM, int RELU, int WF32, int WB16>
__global__ __launch_bounds__(256)
void gemm_bt(const u16* __restrict__ A, const u16* __restrict__ B,
             const float* __restrict__ bias, float* __restrict__ Cf,
             u16* __restrict__ Cb, int M, int N, int K)
{
  constexpr int MFR = BM / 32;            // m-frags per wave
  __shared__ __align__(16) u16 As[BM * 64];
  __shared__ __align__(16) u16 Bs[128 * 64];
  const int tid = threadIdx.x;
  const int wid = tid >> 6, lane = tid & 63;
  const int lo = lane & 15, hi = lane >> 4;
  const int nbn = N >> 7;
  const int cpx = (int)gridDim.x >> 3;
  const int bid = blockIdx.x;
  const int swz = (bid & 7) * cpx + (bid >> 3);
  const int bi = swz / nbn, bj = swz - bi * nbn;
  const size_t row0 = (size_t)bi * BM, col0 = (size_t)bj << 7;
  const int wr = (wid >> 1) * (BM / 2), wc = (wid & 1) << 6;
  // staging: 8 rows/wave/pass; source col pre-swizzled so LDS dest stays linear
  const int srow = (wid << 3) + (lane >> 3);
  const int scol = ((lane & 7) ^ (lane >> 3)) << 3;

  f32x4 acc[MFR][4] = {};

  // read: LDS[r][sl] holds global col-slice sl^(r&7); byte = r*128 + ((g^(r&7))<<4)
  auto rdA = [&](int row, int ks) -> bf16x8 {
    return *(const bf16x8*)((const char*)As + row * 128 + ((((ks << 2) | hi) ^ (row & 7)) << 4));
  };
  auto rdB = [&](int row, int ks) -> bf16x8 {
    return *(const bf16x8*)((const char*)Bs + row * 128 + ((((ks << 2) | hi) ^ (row & 7)) << 4));
  };

  for (int k0 = 0; k0 < K; k0 += 64) {
    __syncthreads();
#pragma unroll
    for (int p = 0; p < BM / 32; ++p)
      gload16(A + (row0 + srow + 32 * p) * (size_t)K + k0 + scol, &As[(wid * 8 + 32 * p) * 64]);
#pragma unroll
    for (int p = 0; p < 4; ++p)
      gload16(B + (col0 + srow + 32 * p) * (size_t)K + k0 + scol, &Bs[(wid * 8 + 32 * p) * 64]);
    __syncthreads();
#pragma unroll
    for (int ks = 0; ks < 2; ++ks) {
      bf16x8 af[MFR], bfr[4];
#pragma unroll
      for (int m = 0; m < MFR; ++m) af[m] = rdA(wr + m * 16 + lo, ks);
#pragma unroll
      for (int n = 0; n < 4; ++n) bfr[n] = rdB(wc + n * 16 + lo, ks);
#pragma unroll
      for (int m = 0; m < MFR; ++m)
#pragma unroll
        for (int n = 0; n < 4; ++n)
          acc[m][n] = __builtin_amdgcn_mfma_f32_16x16x32_bf16(af[m], bfr[n], acc[m][n], 0, 0, 0);
    }
  }

#pragma unroll
  for (int m = 0; m < MFR; ++m)
#pragma unroll
    for (int n = 0; n < 4; ++n) {
      const size_t c = col0 + wc + n * 16 + lo;
      const float bv = bias[c];
#pragma unroll
      for (int i = 0; i < 4; ++i) {
        const size_t r = row0 + wr + m * 16 + hi * 4 + i;
        float v = acc[m][n][i] + bv;
        if (RELU) v = fmaxf(v, 0.0f);
        if (WF32) Cf[r * (size_t)N + c] = v;
        if (WB16) Cb[r * (size_t)N + c] = f2b(v);
      }
    }
}

// ---------------- 256x256 8-phase GEMM (FC projection) ----------------
template<int KC>
__global__ __launch_bounds__(512, 2)
void gemm256(const u16* __restrict__ A, const u16* __restrict__ B,
             const float* __restrict__ bias, float* __restrict__ C,
             int M, int N)
{
  constexpr int T = KC / 64;
  __shared__ __align__(16) u16 LA[2][256 * 64];
  __shared__ __align__(16) u16 LB[2][256 * 64];
  const int tid = threadIdx.x;
  const int wid = tid >> 6, lane = tid & 63;
  const int lo = lane & 15, hi = lane >> 4;
  const int nbn = N >> 8;
  const int cpx = (int)gridDim.x >> 3;
  const int bid = blockIdx.x;
  const int swz = (bid & 7) * cpx + (bid >> 3);
  const int bi = swz / nbn, bj = swz - bi * nbn;
  const size_t row0 = (size_t)bi << 8, col0 = (size_t)bj << 8;
  const int wrow = (wid >> 2) << 7;
  const int wcol = (wid & 3) << 6;

  const int srow = (wid << 3) + (lane >> 3);
  const int scol = ((lane & 7) ^ (lane >> 3)) << 3;
  const u16* srcA = A + (row0 + srow) * (size_t)KC + scol;
  const u16* srcB = B + (col0 + srow) * (size_t)KC + scol;
  const int ldst = wid << 9;

  f32x4 acc[8][4] = {};

  auto stage = [&](int t, int b) {
    const size_t ko = (size_t)t * 64;
#pragma unroll
    for (int i = 0; i < 4; ++i)
      gload16(srcA + ko + (size_t)(i * 64) * KC, &LA[b][ldst + i * 4096]);
#pragma unroll
    for (int i = 0; i < 4; ++i)
      gload16(srcB + ko + (size_t)(i * 64) * KC, &LB[b][ldst + i * 4096]);
  };

  auto rd = [&](const u16* base, int row, int ks) -> bf16x8 {
    const int byte = row * 128 + ((((ks << 2) | hi) ^ (row & 7)) << 4);
    return *(const bf16x8*)((const char*)base + byte);
  };

  stage(0, 0);
  stage(1, 1);

  for (int t = 0; t < T; ++t) {
    const int b = t & 1;
    const u16* Ab = LA[b];
    const u16* Bb = LB[b];
    if (t + 1 < T) { asm volatile("s_waitcnt vmcnt(8)" ::: "memory"); }
    else           { asm volatile("s_waitcnt vmcnt(0)" ::: "memory"); }
    __builtin_amdgcn_sched_barrier(0);
    mbar();

    bf16x8 afr[4], bfr[4];
#pragma unroll
    for (int ks = 0; ks < 2; ++ks) {
#pragma unroll
      for (int m = 0; m < 4; ++m) afr[m] = rd(Ab, wrow + m * 16 + lo, ks);
#pragma unroll
      for (int n = 0; n < 4; ++n) bfr[n] = rd(Bb, wcol + n * 16 + lo, ks);
      mbar();
      asm volatile("s_waitcnt lgkmcnt(0)" ::: "memory");
      __builtin_amdgcn_sched_barrier(0);
      __builtin_amdgcn_s_setprio(1);
#pragma unroll
      for (int m = 0; m < 4; ++m)
#pragma unroll
        for (int n = 0; n < 4; ++n)
          acc[m][n] = __builtin_amdgcn_mfma_f32_16x16x32_bf16(afr[m], bfr[n], acc[m][n], 0, 0, 0);
      __builtin_amdgcn_s_setprio(0);
      mbar();
#pragma unroll
      for (int m = 0; m < 4; ++m) afr[m] = rd(Ab, wrow + (4 + m) * 16 + lo, ks);
      mbar();
      asm volatile("s_waitcnt lgkmcnt(0)" ::: "memory");
      __builtin_amdgcn_sched_barrier(0);
      __builtin_amdgcn_s_setprio(1);
#pragma unroll
      for (int m = 0; m < 4; ++m)
#pragma unroll
        for (int n = 0; n < 4; ++n)
          acc[4 + m][n] = __builtin_amdgcn_mfma_f32_16x16x32_bf16(afr[m], bfr[n], acc[4 + m][n], 0, 0, 0);
      __builtin_amdgcn_s_setprio(0);
      mbar();
    }
    if (t + 2 < T) stage(t + 2, b);   // must stay post-compute: writes buffer b (tile t's)
  }

#pragma unroll
  for (int m = 0; m < 8; ++m)
#pragma unroll
    for (int n = 0; n < 4; ++n) {
      const size_t c = col0 + wcol + n * 16 + lo;
      const float bv = bias[c];
#pragma unroll
      for (int i = 0; i < 4; ++i) {
        const size_t r = row0 + wrow + m * 16 + hi * 4 + i;
        C[r * (size_t)N + c] = acc[m][n][i] + bv;
      }
    }
}

// ---------------- chunk attention: attend over nc=4 chunks (bf16 qkv) ----------------
__global__ __launch_bounds__(64)
void chunk_attn(const u16* __restrict__ qkv, u16* __restrict__ out) {
  const int p = blockIdx.x, h = blockIdx.y, d = threadIdx.x;
  float q[4], k[4], v[4];
#pragma unroll
  for (int c = 0; c < 4; ++c) {
    const u16* b = qkv + (size_t)((c << 10) + p) * 1536 + (h << 6) + d;
    q[c] = b2f(b[0]); k[c] = b2f(b[512]); v[c] = b2f(b[1024]);
  }
  float sc[4][4];
#pragma unroll
  for (int i = 0; i < 4; ++i)
#pragma unroll
    for (int j = 0; j < 4; ++j) sc[i][j] = q[i] * k[j];
#pragma unroll
  for (int mask = 1; mask < 64; mask <<= 1)
#pragma unroll
    for (int i = 0; i < 4; ++i)
#pragma unroll
      for (int j = 0; j < 4; ++j) sc[i][j] += __shfl_xor(sc[i][j], mask);
#pragma unroll
  for (int i = 0; i < 4; ++i) {
    float s0 = sc[i][0] * 0.125f, s1 = sc[i][1] * 0.125f,
          s2 = sc[i][2] * 0.125f, s3 = sc[i][3] * 0.125f;
    const float mx = fmaxf(fmaxf(s0, s1), fmaxf(s2, s3));
    const float e0 = __expf(s0 - mx), e1 = __expf(s1 - mx),
                e2 = __expf(s2 - mx), e3 = __expf(s3 - mx);
    const float inv = 1.0f / (e0 + e1 + e2 + e3);
    const float o = (e0 * v[0] + e1 * v[1] + e2 * v[2] + e3 * v[3]) * inv;
    out[(size_t)((i << 10) + p) * 512 + (h << 6) + d] = f2b(o);
  }
}

// ---------------- global flash attention: swapped QK^T, in-lane softmax ----------------
// 8 waves x 16 q-rows; KV tiles of 64; S^T = mfma(K,Q) so q = lane&15 (softmax in-lane)
__global__ __launch_bounds__(512)
void flash_attn(const u16* __restrict__ qkv, u16* __restrict__ out) {
  __shared__ __align__(16) u16 Ks[64 * 64];
  __shared__ __align__(16) u16 Vt[64 * 64];
  __shared__ __align__(16) u16 Pp[8][16 * 64];   // wave-private P, swizzled [q_lo][k]
  const int tid = threadIdx.x, wid = tid >> 6, lane = tid & 63;
  const int lo = lane & 15, hi = lane >> 4;
  const int q0 = blockIdx.x << 7, h = blockIdx.y;
  const int hoff = h << 6;
  char* KsB = (char*)Ks; char* VtB = (char*)Vt;
  char* Pw = (char*)&Pp[wid][0];
  const int xsw = (lo & 7) << 4;
  constexpr float C1 = 0.18033688011112042f;   // 0.125 * log2(e)

  bf16x8 qf[2];
#pragma unroll
  for (int kh = 0; kh < 2; ++kh)
    qf[kh] = *(const bf16x8*)(qkv + (size_t)(q0 + wid * 16 + lo) * 1536 + hoff + kh * 32 + hi * 8);

  f32x4 o[4] = {};
  float mr = -3e38f, lr = 0.f;     // raw-score online-softmax state for q = lo

  const int krow = tid >> 3, kq = tid & 7;

  bf16x8 kpre = *(const bf16x8*)(qkv + (size_t)krow * 1536 + 512 + hoff + kq * 8);
  bf16x8 vpre = *(const bf16x8*)(qkv + (size_t)krow * 1536 + 1024 + hoff + kq * 8);

  for (int kv0 = 0; kv0 < 4096; kv0 += 64) {
    __syncthreads();
    *(bf16x8*)(KsB + ((krow * 128 + kq * 16) ^ ((krow & 7) << 4))) = kpre;
    // V pair-pack transpose: exchange 8B with krow^1 partner, write 4 x b32
    {
      const unsigned* vp = (const unsigned*)&vpre;
      const int oddr = krow & 1;
      const unsigned t0 = oddr ? vp[0] : vp[2];
      const unsigned t1 = oddr ? vp[1] : vp[3];
      const unsigned r0 = (unsigned)__shfl_xor((int)t0, 8);
      const unsigned r1 = (unsigned)__shfl_xor((int)t1, 8);
      const unsigned E0 = oddr ? r0 : vp[0];   // j-even source (dd pair 0)
      const unsigned E1 = oddr ? r1 : vp[1];
      const unsigned O0 = oddr ? vp[2] : r0;   // j-odd source
      const unsigned O1 = oddr ? vp[3] : r1;
      const int jp = krow & ~1;
      const int db = kq * 8 + oddr * 4;
      unsigned w0 = (E0 & 0xffffu) | (O0 << 16);
      unsigned w1 = (E0 >> 16) | (O0 & 0xffff0000u);
      unsigned w2 = (E1 & 0xffffu) | (O1 << 16);
      unsigned w3 = (E1 >> 16) | (O1 & 0xffff0000u);
      *(unsigned*)(VtB + (((db + 0) * 128 + 2 * jp) ^ (((db + 0) & 7) << 4))) = w0;
      *(unsigned*)(VtB + (((db + 1) * 128 + 2 * jp) ^ (((db + 1) & 7) << 4))) = w1;
      *(unsigned*)(VtB + (((db + 2) * 128 + 2 * jp) ^ (((db + 2) & 7) << 4))) = w2;
      *(unsigned*)(VtB + (((db + 3) * 128 + 2 * jp) ^ (((db + 3) & 7) << 4))) = w3;
    }
    __syncthreads();
    if (kv0 + 64 < 4096) {
      kpre = *(const bf16x8*)(qkv + (size_t)(kv0 + 64 + krow) * 1536 + 512 + hoff + kq * 8);
      vpre = *(const bf16x8*)(qkv + (size_t)(kv0 + 64 + krow) * 1536 + 1024 + hoff + kq * 8);
    }

    // S^T (raw scores): rows = keys, col = q = lo
    f32x4 s[4] = {};
#pragma unroll
    for (int n = 0; n < 4; ++n) {
      const int key = n * 16 + lo;
#pragma unroll
      for (int kh = 0; kh < 2; ++kh) {
        bf16x8 kf = *(const bf16x8*)(KsB + ((key * 128 + kh * 64 + hi * 16) ^ ((key & 7) << 4)));
        s[n] = __builtin_amdgcn_mfma_f32_16x16x32_bf16(kf, qf[kh], s[n], 0, 0, 0);
      }
    }

    float pm = s[0][0];
#pragma unroll
    for (int n = 0; n < 4; ++n)
#pragma unroll
      for (int i = 0; i < 4; ++i) pm = fmaxf(pm, s[n][i]);
    pm = fmaxf(pm, __shfl_xor(pm, 16));
    pm = fmaxf(pm, __shfl_xor(pm, 32));

    if (__any(pm > mr + 64.f)) {         // defer-max: 64 raw = 8 scaled
      const float mn = fmaxf(mr, pm);
      const float sc = exp2f((mr - mn) * C1);
      mr = mn;
      lr *= sc;
#pragma unroll
      for (int i = 0; i < 4; ++i) {
        const float sq = __shfl(sc, hi * 4 + i);
#pragma unroll
        for (int n = 0; n < 4; ++n) o[n][i] *= sq;
      }
    }

    // P = exp2(s*C1 - mc); pack to bf16; wave-private LDS write (4 x b64)
    const float mc = mr * C1;
    float rs = 0.f;
    unsigned U[8];
#pragma unroll
    for (int n = 0; n < 4; ++n) {
      const float p0 = exp2f(fmaf(s[n][0], C1, -mc));
      const float p1 = exp2f(fmaf(s[n][1], C1, -mc));
      const float p2 = exp2f(fmaf(s[n][2], C1, -mc));
      const float p3 = exp2f(fmaf(s[n][3], C1, -mc));
      rs += (p0 + p1) + (p2 + p3);
      asm("v_cvt_pk_bf16_f32 %0, %1, %2" : "=v"(U[2 * n])     : "v"(p0), "v"(p1));
      asm("v_cvt_pk_bf16_f32 %0, %1, %2" : "=v"(U[2 * n + 1]) : "v"(p2), "v"(p3));
    }
    rs += __shfl_xor(rs, 16);
    rs += __shfl_xor(rs, 32);
    lr += rs;
#pragma unroll
    for (int n = 0; n < 4; ++n) {
      const int off = lo * 128 + ((n * 32 + hi * 8) ^ xsw);
      const unsigned long long dw = (unsigned long long)U[2 * n] |
                                    ((unsigned long long)U[2 * n + 1] << 32);
      *(unsigned long long*)(Pw + off) = dw;
    }

    // PV
#pragma unroll
    for (int kh = 0; kh < 2; ++kh) {
      bf16x8 pa = *(const bf16x8*)(Pw + lo * 128 + ((kh * 64 + hi * 16) ^ xsw));
#pragma unroll
      for (int n = 0; n < 4; ++n) {
        const int vd = n * 16 + lo;
        bf16x8 vf = *(const bf16x8*)(VtB + ((vd * 128 + kh * 64 + hi * 16) ^ ((vd & 7) << 4)));
        o[n] = __builtin_amdgcn_mfma_f32_16x16x32_bf16(pa, vf, o[n], 0, 0, 0);
      }
    }
  }

#pragma unroll
  for (int i = 0; i < 4; ++i) {
    const float lq = __shfl(lr, hi * 4 + i);
    const float inv = 1.0f / lq;
    const int r = q0 + wid * 16 + hi * 4 + i;
#pragma unroll
    for (int n = 0; n < 4; ++n)
      out[(size_t)r * 512 + hoff + n * 16 + lo] = f2b(o[n][i] * inv);
  }
}

// ---------------- residual add + LayerNorm ----------------
__global__ __launch_bounds__(256)
void add_ln(const float* __restrict__ a, const float* __restrict__ b,
            const float* __restrict__ g, const float* __restrict__ be,
            float* __restrict__ of, u16* __restrict__ ob) {
  const int wid = threadIdx.x >> 6, lane = threadIdx.x & 63;
  const int row = blockIdx.x * 4 + wid;
  const size_t base = (size_t)row * 512 + lane * 8;
  float4 a0 = *(const float4*)(a + base), a1 = *(const float4*)(a + base + 4);
  float4 b0 = *(const float4*)(b + base), b1 = *(const float4*)(b + base + 4);
  float x[8] = {a0.x + b0.x, a0.y + b0.y, a0.z + b0.z, a0.w + b0.w,
                a1.x + b1.x, a1.y + b1.y, a1.z + b1.z, a1.w + b1.w};
  float s = 0.f, sq = 0.f;
#pragma unroll
  for (int j = 0; j < 8; ++j) { s += x[j]; sq += x[j] * x[j]; }
#pragma unroll
  for (int mask = 1; mask < 64; mask <<= 1) {
    s += __shfl_xor(s, mask);
    sq += __shfl_xor(sq, mask);
  }
  const float mean = s * (1.0f / 512.0f);
  const float var = sq * (1.0f / 512.0f) - mean * mean;
  const float rstd = rsqrtf(var + 1e-5f);
  float4 g0 = *(const float4*)(g + lane * 8), g1 = *(const float4*)(g + lane * 8 + 4);
  float4 e0 = *(const float4*)(be + lane * 8), e1 = *(const float4*)(be + lane * 8 + 4);
  const float gg[8] = {g0.x, g0.y, g0.z, g0.w, g1.x, g1.y, g1.z, g1.w};
  const float bb[8] = {e0.x, e0.y, e0.z, e0.w, e1.x, e1.y, e1.z, e1.w};
#pragma unroll
  for (int j = 0; j < 8; ++j) {
    const float y = (x[j] - mean) * rstd * gg[j] + bb[j];
    of[base + j] = y;
    ob[base + j] = f2b(y);
  }
}

extern "C" void kernel_launch(void* const* d_in, const int* in_sizes, int n_in,
                              void* d_out, int out_size, void* d_ws, size_t ws_size,
                              hipStream_t stream) {
  (void)in_sizes; (void)n_in; (void)out_size; (void)ws_size;
  const int*   tokens = (const int*)d_in[0];
  const float* emb    = (const float*)d_in[1];
  const float* cwin   = (const float*)d_in[2];
  const float* cbin   = (const float*)d_in[3];
  const float* cwout  = (const float*)d_in[4];
  const float* cbout  = (const float*)d_in[5];
  const float* gwin   = (const float*)d_in[6];
  const float* gbin   = (const float*)d_in[7];
  const float* gwout  = (const float*)d_in[8];
  const float* gbout  = (const float*)d_in[9];
  const float* ln1g   = (const float*)d_in[10];
  const float* ln1b   = (const float*)d_in[11];
  const float* fw1    = (const float*)d_in[12];
  const float* fb1    = (const float*)d_in[13];
  const float* fw2    = (const float*)d_in[14];
  const float* fb2    = (const float*)d_in[15];
  const float* ln2g   = (const float*)d_in[16];
  const float* ln2b   = (const float*)d_in[17];
  const float* fcw    = (const float*)d_in[18];
  const float* fcb    = (const float*)d_in[19];
  float* out = (float*)d_out;

  char* ws = (char*)d_ws;
  size_t off = 0;
  auto alloc = [&](size_t bytes) -> void* {
    void* p = ws + off;
    off += (bytes + 255) & ~(size_t)255;
    return p;
  };
  u16*   xb    = (u16*)alloc((size_t)4096 * 512 * 2);
  float* xf    = (float*)alloc((size_t)4096 * 512 * 4);
  u16*   qkv1b = (u16*)alloc((size_t)4096 * 1536 * 2);
  u16*   at1   = (u16*)alloc((size_t)4096 * 512 * 2);
  u16*   cab   = (u16*)alloc((size_t)4096 * 512 * 2);
  u16*   qkv2  = (u16*)alloc((size_t)4096 * 1536 * 2);
  u16*   at2   = (u16*)alloc((size_t)4096 * 512 * 2);
  float* gaf   = (float*)alloc((size_t)4096 * 512 * 4);
  float* x1f   = (float*)alloc((size_t)4096 * 512 * 4);
  u16*   x1b   = (u16*)alloc((size_t)4096 * 512 * 2);
  u16*   f1b   = (u16*)alloc((size_t)4096 * 2048 * 2);
  float* ff    = (float*)alloc((size_t)4096 * 512 * 4);
  float* x2f   = (float*)alloc((size_t)4096 * 512 * 4);
  u16*   x2b   = (u16*)alloc((size_t)4096 * 512 * 2);
  u16*   wcinb  = (u16*)alloc((size_t)1536 * 512 * 2);
  u16*   wcoutb = (u16*)alloc((size_t)512 * 512 * 2);
  u16*   wginb  = (u16*)alloc((size_t)1536 * 512 * 2);
  u16*   wgoutb = (u16*)alloc((size_t)512 * 512 * 2);
  u16*   wf1b   = (u16*)alloc((size_t)2048 * 512 * 2);
  u16*   wf2b   = (u16*)alloc((size_t)512 * 2048 * 2);
  u16*   wfcb   = (u16*)alloc((size_t)32000 * 512 * 2);

  f2b_multi<<<2048, 256, 0, stream>>>(
      (const float4*)cwin, wcinb, (const float4*)cwout, wcoutb,
      (const float4*)gwin, wginb, (const float4*)gwout, wgoutb,
      (const float4*)fw1, wf1b, (const float4*)fw2, wf2b,
      (const float4*)fcw, wfcb);

  embed_pe<<<4096, 256, 0, stream>>>(tokens, emb, xf, xb);

  // chunk stage
  gemm_bt<128, 0, 0, 1><<<384, 256, 0, stream>>>(xb, wcinb, cbin, (float*)nullptr, qkv1b, 4096, 1536, 512);
  chunk_attn<<<dim3(1024, 8), 64, 0, stream>>>(qkv1b, at1);
  gemm_bt<64, 0, 0, 1><<<256, 256, 0, stream>>>(at1, wcoutb, cbout, (float*)nullptr, cab, 4096, 512, 512);

  // global stage
  gemm_bt<128, 0, 0, 1><<<384, 256, 0, stream>>>(cab, wginb, gbin, (float*)nullptr, qkv2, 4096, 1536, 512);
  flash_attn<<<dim3(32, 8), 512, 0, stream>>>(qkv2, at2);
  gemm_bt<64, 0, 1, 0><<<256, 256, 0, stream>>>(at2, wgoutb, gbout, gaf, (u16*)nullptr, 4096, 512, 512);

  // post-norm encoder layer
  add_ln<<<1024, 256, 0, stream>>>(xf, gaf, ln1g, ln1b, x1f, x1b);
  gemm_bt<128, 1, 0, 1><<<512, 256, 0, stream>>>(x1b, wf1b, fb1, (float*)nullptr, f1b, 4096, 2048, 512);
  gemm_bt<64, 0, 1, 0><<<256, 256, 0, stream>>>(f1b, wf2b, fb2, ff, (u16*)nullptr, 4096, 512, 2048);
  add_ln<<<1024, 256, 0, stream>>>(x1f, ff, ln2g, ln2b, x2f, x2b);

  // vocab projection
  gemm256<512><<<2000, 512, 0, stream>>>(x2b, wfcb, fcb, out, 4096, 32000);
}